// Round 5
// baseline (3003.486 us; speedup 1.0000x reference)
//
#include <hip/hip_runtime.h>
#include <cstddef>

#define HH 720
#define WW 1280
#define FRAME 1843200            // 2*720*1280
#define FRAME4 460800            // FRAME/4
#define T_EVT 10
#define T_TOTAL 20
#define NBLK 256
#define NTHR 1024
#define NT (NBLK * NTHR)         // 262144 scan threads
#define NWAVES (NBLK * (NTHR / 64))   // 4096 waves
#define ARRIVE64 (1ULL << 32)    // arrival token in high 32 bits; count in low 32

// Persistent device globals for the tiny scalar state.
__device__ unsigned g_minkey;
__device__ unsigned g_maxkey;
__device__ unsigned long long g_count[T_TOTAL];  // lo32: spike count, hi32: wave arrivals

// Monotonic float<->uint key mapping (total order preserved).
__device__ __forceinline__ unsigned f2key(float f) {
    unsigned b = __float_as_uint(f);
    return b ^ ((unsigned)(((int)b) >> 31) | 0x80000000u);
}
__device__ __forceinline__ float key2f(unsigned k) {
    unsigned b = (k & 0x80000000u) ? (k ^ 0x80000000u) : ~k;
    return __uint_as_float(b);
}

__global__ void init_kernel() {
    if (threadIdx.x == 0) { g_minkey = 0xFFFFFFFFu; g_maxkey = 0u; }
    if (threadIdx.x < T_TOTAL) g_count[threadIdx.x] = 0ull;
}

// min/max of t (float4-vectorized), fused with zeroing the histogram region.
// Kernel boundary before scatter_kernel guarantees both complete + coherent.
__global__ void minmax_zero_kernel(const float* __restrict__ t, int n,
                                   float4* __restrict__ hist4) {
    const int gtid = blockIdx.x * blockDim.x + threadIdx.x;
    const int gstride = gridDim.x * blockDim.x;

    const float4 z = make_float4(0.f, 0.f, 0.f, 0.f);
    for (int i = gtid; i < T_EVT * FRAME4; i += gstride) hist4[i] = z;

    unsigned mn = 0xFFFFFFFFu, mx = 0u;
    const int n4 = n >> 2;
    const float4* t4 = (const float4*)t;
    for (int i = gtid; i < n4; i += gstride) {
        float4 tv = t4[i];
        unsigned k0 = f2key(tv.x), k1 = f2key(tv.y);
        unsigned k2 = f2key(tv.z), k3 = f2key(tv.w);
        unsigned a = k0 < k1 ? k0 : k1, b = k2 < k3 ? k2 : k3;
        unsigned c = a < b ? a : b;
        mn = mn < c ? mn : c;
        a = k0 > k1 ? k0 : k1; b = k2 > k3 ? k2 : k3;
        c = a > b ? a : b;
        mx = mx > c ? mx : c;
    }
    for (int i = (n4 << 2) + gtid; i < n; i += gstride) {  // tail
        unsigned k = f2key(t[i]);
        mn = mn < k ? mn : k;
        mx = mx > k ? mx : k;
    }
    for (int off = 32; off > 0; off >>= 1) {
        unsigned omn = (unsigned)__shfl_down((int)mn, off, 64);
        unsigned omx = (unsigned)__shfl_down((int)mx, off, 64);
        mn = mn < omn ? mn : omn;
        mx = mx > omx ? mx : omx;
    }
    __shared__ unsigned smn[16], smx[16];
    int lane = threadIdx.x & 63, wv = threadIdx.x >> 6;
    if (lane == 0) { smn[wv] = mn; smx[wv] = mx; }
    __syncthreads();
    if (threadIdx.x == 0) {
        int nw = blockDim.x >> 6;
        for (int i = 1; i < nw; ++i) {
            mn = mn < smn[i] ? mn : smn[i];
            mx = mx > smx[i] ? mx : smx[i];
        }
        atomicMin(&g_minkey, mn);
        atomicMax(&g_maxkey, mx);
    }
}

// 1 event/thread (R2 config: best measured), u32 atomics on the count grid.
__global__ void scatter_kernel(const int* __restrict__ x, const int* __restrict__ y,
                               const int* __restrict__ p, const float* __restrict__ t,
                               unsigned* __restrict__ hist, int n) {
#pragma clang fp contract(off)
    int i = blockIdx.x * blockDim.x + threadIdx.x;
    if (i >= n) return;
    float tmin = key2f(g_minkey);
    float tmax = key2f(g_maxkey);
    float tv = t[i];
    float tn;
    if (tmax > tmin) {
        // exact reference op order: ((t - tmin) / denom) * (10 - 1e-6), fp32 IEEE
        tn = (tv - tmin) / (tmax - tmin) * (float)(10.0 - 1e-6);
    } else {
        tn = 0.0f;
    }
    int ti = (int)tn;                     // trunc toward zero, tn >= 0
    ti = ti < 0 ? 0 : (ti > T_EVT - 1 ? T_EVT - 1 : ti);
    int xi = x[i]; xi = xi < 0 ? 0 : (xi > WW - 1 ? WW - 1 : xi);
    int yi = y[i]; yi = yi < 0 ? 0 : (yi > HH - 1 ? HH - 1 : yi);
    int ci = p[i];                        // p in {0,1}, used directly per reference
    size_t off = (size_t)ti * FRAME + (size_t)ci * (HH * WW) + (size_t)yi * WW + xi;
    atomicAdd(hist + off, 1u);           // integer count; cvt to f32 at scan load = exact
}

// Cooperative scan with ZERO __syncthreads in the loop: per-wave shuffle reduce
// + one packed u64 atomic per wave (count lo32, arrivals hi32); lane 0 spins on
// relaxed agent loads, then shfl-broadcasts. No barrier -> no vmcnt(0) drains:
// spike stores retire in background across steps; prefetched hist stays uint4
// and is converted at USE (after the spin), so its waitcnt lands post-barrier.
// hist frames live in out[(10+s)*FRAME]; step 10+s overwrites that region at
// the SAME per-thread indices -> same-lane same-address ordering suffices.
__global__ __launch_bounds__(NTHR) void scan_kernel(float* __restrict__ out) {
#pragma clang fp contract(off)
    const float decay = (float)0.9048374180359595;  // float32(exp(-1/10))
    const int gtid = blockIdx.x * NTHR + threadIdx.x;
    const int lane = threadIdx.x & 63;
    const uint4 uz = make_uint4(0u, 0u, 0u, 0u);

    float4 mem0 = make_float4(0.f, 0.f, 0.f, 0.f);
    float4 mem1 = make_float4(0.f, 0.f, 0.f, 0.f);
    const bool has1 = (gtid + NT) < FRAME4;   // k=0 always valid (NT <= FRAME4)
    float thr = 1.0f;

    // preload step 0's frame as raw uint counts
    uint4 u0, u1;
    {
        const uint4* h = (const uint4*)(out + (size_t)T_EVT * FRAME);
        u0 = h[gtid];
        u1 = has1 ? h[gtid + NT] : uz;
    }

    for (int s = 0; s < T_TOTAL; ++s) {
        float4* o4 = (float4*)(out + (size_t)s * FRAME);
        int cnt = 0;

        {   // k = 0  (u->f conversion here, AFTER the previous step's spin)
            float4 m, spk;
            m.x = mem0.x * decay; m.x = m.x + (float)u0.x;
            m.y = mem0.y * decay; m.y = m.y + (float)u0.y;
            m.z = mem0.z * decay; m.z = m.z + (float)u0.z;
            m.w = mem0.w * decay; m.w = m.w + (float)u0.w;
            spk.x = (m.x >= thr) ? 1.0f : 0.0f;
            spk.y = (m.y >= thr) ? 1.0f : 0.0f;
            spk.z = (m.z >= thr) ? 1.0f : 0.0f;
            spk.w = (m.w >= thr) ? 1.0f : 0.0f;
            o4[gtid] = spk;
            mem0.x = m.x - spk.x * thr;
            mem0.y = m.y - spk.y * thr;
            mem0.z = m.z - spk.z * thr;
            mem0.w = m.w - spk.w * thr;
            cnt += (int)spk.x + (int)spk.y + (int)spk.z + (int)spk.w;
        }
        if (has1) {   // k = 1
            float4 m, spk;
            m.x = mem1.x * decay; m.x = m.x + (float)u1.x;
            m.y = mem1.y * decay; m.y = m.y + (float)u1.y;
            m.z = mem1.z * decay; m.z = m.z + (float)u1.z;
            m.w = mem1.w * decay; m.w = m.w + (float)u1.w;
            spk.x = (m.x >= thr) ? 1.0f : 0.0f;
            spk.y = (m.y >= thr) ? 1.0f : 0.0f;
            spk.z = (m.z >= thr) ? 1.0f : 0.0f;
            spk.w = (m.w >= thr) ? 1.0f : 0.0f;
            o4[gtid + NT] = spk;
            mem1.x = m.x - spk.x * thr;
            mem1.y = m.y - spk.y * thr;
            mem1.z = m.z - spk.z * thr;
            mem1.w = m.w - spk.w * thr;
            cnt += (int)spk.x + (int)spk.y + (int)spk.z + (int)spk.w;
        }

        // prefetch step s+1's frame (raw uint4; stays in flight through the spin)
        if (s + 1 < T_EVT) {
            const uint4* hn = (const uint4*)(out + (size_t)(T_EVT + s + 1) * FRAME);
            u0 = hn[gtid];
            u1 = has1 ? hn[gtid + NT] : uz;
        } else {
            u0 = uz; u1 = uz;
        }

        if (s == T_TOTAL - 1) break;   // last step's count is never consumed

        // per-wave reduce (registers only) -> one u64 atomic per wave
        for (int off = 32; off > 0; off >>= 1) cnt += __shfl_down(cnt, off, 64);
        unsigned total;
        if (lane == 0) {
            __hip_atomic_fetch_add(&g_count[s], (unsigned long long)(unsigned)cnt + ARRIVE64,
                                   __ATOMIC_RELAXED, __HIP_MEMORY_SCOPE_AGENT);
            unsigned long long v;
            do {
                __builtin_amdgcn_s_sleep(2);
                v = __hip_atomic_load(&g_count[s], __ATOMIC_RELAXED,
                                      __HIP_MEMORY_SCOPE_AGENT);
            } while ((unsigned)(v >> 32) != NWAVES);
            total = (unsigned)v;
        }
        total = (unsigned)__shfl((int)total, 0, 64);
        float rate = (float)total / 1843200.0f;  // exact count; one IEEE div = mean
        thr = thr + 0.1f * (rate - 0.1f);
        thr = fminf(fmaxf(thr, 0.1f), 10.0f);
    }
}

extern "C" void kernel_launch(void* const* d_in, const int* in_sizes, int n_in,
                              void* d_out, int out_size, void* d_ws, size_t ws_size,
                              hipStream_t stream) {
    const int*   x = (const int*)d_in[0];
    const int*   y = (const int*)d_in[1];
    const int*   p = (const int*)d_in[2];
    const float* t = (const float*)d_in[3];
    float* out = (float*)d_out;
    const int n = in_sizes[0];

    float* hist = out + (size_t)T_EVT * FRAME;   // steps 10..19 region doubles as hist

    init_kernel<<<1, 64, 0, stream>>>();
    minmax_zero_kernel<<<1024, 256, 0, stream>>>(t, n, (float4*)hist);
    scatter_kernel<<<(n + 255) / 256, 256, 0, stream>>>(x, y, p, t,
                                                        (unsigned*)hist, n);

    dim3 g(NBLK), b(NTHR);
    void* args[] = { (void*)&out };
    hipLaunchCooperativeKernel((void*)scan_kernel, g, b, args, 0, stream);
}

// Round 6
// 513.016 us; speedup vs baseline: 5.8546x; 5.8546x over previous
//
#include <hip/hip_runtime.h>
#include <cstddef>

#define HH 720
#define WW 1280
#define FRAME 1843200            // 2*720*1280
#define FRAME4 460800            // FRAME/4
#define T_EVT 10
#define T_TOTAL 20
#define NBLK 256
#define NTHR 1024
#define NWPB (NTHR / 64)         // 16 waves per block
#define NT (NBLK * NTHR)         // 262144 scan threads
#define ARRIVE64 (1ULL << 32)    // arrival token hi32; count lo32 (256 blocks/step)

// Persistent device globals for the tiny scalar state.
__device__ unsigned g_minkey;
__device__ unsigned g_maxkey;
__device__ unsigned long long g_count[T_TOTAL];  // lo32: spike count, hi32: block arrivals

// Monotonic float<->uint key mapping (total order preserved).
__device__ __forceinline__ unsigned f2key(float f) {
    unsigned b = __float_as_uint(f);
    return b ^ ((unsigned)(((int)b) >> 31) | 0x80000000u);
}
__device__ __forceinline__ float key2f(unsigned k) {
    unsigned b = (k & 0x80000000u) ? (k ^ 0x80000000u) : ~k;
    return __uint_as_float(b);
}

__global__ void init_kernel() {
    if (threadIdx.x == 0) { g_minkey = 0xFFFFFFFFu; g_maxkey = 0u; }
    if (threadIdx.x < T_TOTAL) g_count[threadIdx.x] = 0ull;
}

// min/max of t (float4-vectorized), fused with zeroing the histogram region.
// Kernel boundary before scatter_kernel guarantees both complete + coherent.
__global__ void minmax_zero_kernel(const float* __restrict__ t, int n,
                                   float4* __restrict__ hist4) {
    const int gtid = blockIdx.x * blockDim.x + threadIdx.x;
    const int gstride = gridDim.x * blockDim.x;

    const float4 z = make_float4(0.f, 0.f, 0.f, 0.f);
    for (int i = gtid; i < T_EVT * FRAME4; i += gstride) hist4[i] = z;

    unsigned mn = 0xFFFFFFFFu, mx = 0u;
    const int n4 = n >> 2;
    const float4* t4 = (const float4*)t;
    for (int i = gtid; i < n4; i += gstride) {
        float4 tv = t4[i];
        unsigned k0 = f2key(tv.x), k1 = f2key(tv.y);
        unsigned k2 = f2key(tv.z), k3 = f2key(tv.w);
        unsigned a = k0 < k1 ? k0 : k1, b = k2 < k3 ? k2 : k3;
        unsigned c = a < b ? a : b;
        mn = mn < c ? mn : c;
        a = k0 > k1 ? k0 : k1; b = k2 > k3 ? k2 : k3;
        c = a > b ? a : b;
        mx = mx > c ? mx : c;
    }
    for (int i = (n4 << 2) + gtid; i < n; i += gstride) {  // tail
        unsigned k = f2key(t[i]);
        mn = mn < k ? mn : k;
        mx = mx > k ? mx : k;
    }
    for (int off = 32; off > 0; off >>= 1) {
        unsigned omn = (unsigned)__shfl_down((int)mn, off, 64);
        unsigned omx = (unsigned)__shfl_down((int)mx, off, 64);
        mn = mn < omn ? mn : omn;
        mx = mx > omx ? mx : omx;
    }
    __shared__ unsigned smn[16], smx[16];
    int lane = threadIdx.x & 63, wv = threadIdx.x >> 6;
    if (lane == 0) { smn[wv] = mn; smx[wv] = mx; }
    __syncthreads();
    if (threadIdx.x == 0) {
        int nw = blockDim.x >> 6;
        for (int i = 1; i < nw; ++i) {
            mn = mn < smn[i] ? mn : smn[i];
            mx = mx > smx[i] ? mx : smx[i];
        }
        atomicMin(&g_minkey, mn);
        atomicMax(&g_maxkey, mx);
    }
}

// 1 event/thread, u32 atomics on the count grid (integer RMW > fp32 RMW at L2;
// scan converts u32->f32 at load, bit-exact vs fp32 +1.0 accumulation).
__global__ void scatter_kernel(const int* __restrict__ x, const int* __restrict__ y,
                               const int* __restrict__ p, const float* __restrict__ t,
                               unsigned* __restrict__ hist, int n) {
#pragma clang fp contract(off)
    int i = blockIdx.x * blockDim.x + threadIdx.x;
    if (i >= n) return;
    float tmin = key2f(g_minkey);
    float tmax = key2f(g_maxkey);
    float tv = t[i];
    float tn;
    if (tmax > tmin) {
        // exact reference op order: ((t - tmin) / denom) * (10 - 1e-6), fp32 IEEE
        tn = (tv - tmin) / (tmax - tmin) * (float)(10.0 - 1e-6);
    } else {
        tn = 0.0f;
    }
    int ti = (int)tn;                     // trunc toward zero, tn >= 0
    ti = ti < 0 ? 0 : (ti > T_EVT - 1 ? T_EVT - 1 : ti);
    int xi = x[i]; xi = xi < 0 ? 0 : (xi > WW - 1 ? WW - 1 : xi);
    int yi = y[i]; yi = yi < 0 ? 0 : (yi > HH - 1 ? HH - 1 : yi);
    int ci = p[i];                        // p in {0,1}, used directly per reference
    size_t off = (size_t)ti * FRAME + (size_t)ci * (HH * WW) + (size_t)yi * WW + xi;
    atomicAdd(hist + off, 1u);
}

// Cooperative scan, hierarchical barrier, ZERO __syncthreads in the loop:
//   wave shuffle-reduce -> per-wave LDS packed atomic (ds_add_rtn; count in
//   lo16, arrivals at bit 16) -> LAST-arriving wave does the block's single
//   global u64 atomic (256/step — the proven R2/R4 spinner count) and spins,
//   then publishes via a per-step LDS flag; other 15 waves spin on LDS only
//   (lgkmcnt — their spike stores + uint4 prefetches stay in flight).
// hist frames live in out[(10+s)*FRAME]; step 10+s overwrites that region at
// the SAME per-thread indices -> same-lane same-address ordering suffices.
__global__ __launch_bounds__(NTHR) void scan_kernel(float* __restrict__ out) {
#pragma clang fp contract(off)
    const float decay = (float)0.9048374180359595;  // float32(exp(-1/10))
    const int gtid = blockIdx.x * NTHR + threadIdx.x;
    const int lane = threadIdx.x & 63;
    const uint4 uz = make_uint4(0u, 0u, 0u, 0u);

    float4 mem0 = make_float4(0.f, 0.f, 0.f, 0.f);
    float4 mem1 = make_float4(0.f, 0.f, 0.f, 0.f);
    const bool has1 = (gtid + NT) < FRAME4;   // k=0 always valid (NT <= FRAME4)
    float thr = 1.0f;

    __shared__ unsigned lds_arr[T_TOTAL];   // per-step: count lo16 | arrivals<<16
    __shared__ unsigned lds_tot[T_TOTAL];   // per-step: global total + 1 (0 = not ready)
    if (threadIdx.x < T_TOTAL) { lds_arr[threadIdx.x] = 0u; lds_tot[threadIdx.x] = 0u; }
    __syncthreads();   // once, outside the loop

    // preload step 0's frame as raw uint counts
    uint4 u0, u1;
    {
        const uint4* h = (const uint4*)(out + (size_t)T_EVT * FRAME);
        u0 = h[gtid];
        u1 = has1 ? h[gtid + NT] : uz;
    }

    for (int s = 0; s < T_TOTAL; ++s) {
        float4* o4 = (float4*)(out + (size_t)s * FRAME);
        int cnt = 0;

        {   // k = 0  (u->f conversion here, after the previous step's wait)
            float4 m, spk;
            m.x = mem0.x * decay; m.x = m.x + (float)u0.x;
            m.y = mem0.y * decay; m.y = m.y + (float)u0.y;
            m.z = mem0.z * decay; m.z = m.z + (float)u0.z;
            m.w = mem0.w * decay; m.w = m.w + (float)u0.w;
            spk.x = (m.x >= thr) ? 1.0f : 0.0f;
            spk.y = (m.y >= thr) ? 1.0f : 0.0f;
            spk.z = (m.z >= thr) ? 1.0f : 0.0f;
            spk.w = (m.w >= thr) ? 1.0f : 0.0f;
            o4[gtid] = spk;
            mem0.x = m.x - spk.x * thr;
            mem0.y = m.y - spk.y * thr;
            mem0.z = m.z - spk.z * thr;
            mem0.w = m.w - spk.w * thr;
            cnt += (int)spk.x + (int)spk.y + (int)spk.z + (int)spk.w;
        }
        if (has1) {   // k = 1
            float4 m, spk;
            m.x = mem1.x * decay; m.x = m.x + (float)u1.x;
            m.y = mem1.y * decay; m.y = m.y + (float)u1.y;
            m.z = mem1.z * decay; m.z = m.z + (float)u1.z;
            m.w = mem1.w * decay; m.w = m.w + (float)u1.w;
            spk.x = (m.x >= thr) ? 1.0f : 0.0f;
            spk.y = (m.y >= thr) ? 1.0f : 0.0f;
            spk.z = (m.z >= thr) ? 1.0f : 0.0f;
            spk.w = (m.w >= thr) ? 1.0f : 0.0f;
            o4[gtid + NT] = spk;
            mem1.x = m.x - spk.x * thr;
            mem1.y = m.y - spk.y * thr;
            mem1.z = m.z - spk.z * thr;
            mem1.w = m.w - spk.w * thr;
            cnt += (int)spk.x + (int)spk.y + (int)spk.z + (int)spk.w;
        }

        // prefetch step s+1's frame (raw uint4; stays in flight through the wait)
        if (s + 1 < T_EVT) {
            const uint4* hn = (const uint4*)(out + (size_t)(T_EVT + s + 1) * FRAME);
            u0 = hn[gtid];
            u1 = has1 ? hn[gtid + NT] : uz;
        } else {
            u0 = uz; u1 = uz;
        }

        if (s == T_TOTAL - 1) break;   // last step's count is never consumed

        for (int off = 32; off > 0; off >>= 1) cnt += __shfl_down(cnt, off, 64);
        unsigned total;
        if (lane == 0) {
            unsigned old = __hip_atomic_fetch_add(&lds_arr[s],
                               (unsigned)cnt + (1u << 16),
                               __ATOMIC_RELAXED, __HIP_MEMORY_SCOPE_WORKGROUP);
            if ((old >> 16) == NWPB - 1) {
                // last wave of this block: block total = old.lo16 + my cnt
                unsigned blockcnt = (old + (unsigned)cnt) & 0xFFFFu;
                __hip_atomic_fetch_add(&g_count[s],
                                       (unsigned long long)blockcnt + ARRIVE64,
                                       __ATOMIC_RELAXED, __HIP_MEMORY_SCOPE_AGENT);
                unsigned long long v;
                do {
                    __builtin_amdgcn_s_sleep(2);
                    v = __hip_atomic_load(&g_count[s], __ATOMIC_RELAXED,
                                          __HIP_MEMORY_SCOPE_AGENT);
                } while ((unsigned)(v >> 32) != NBLK);
                total = (unsigned)v;
                __hip_atomic_store(&lds_tot[s], total + 1u,
                                   __ATOMIC_RELAXED, __HIP_MEMORY_SCOPE_WORKGROUP);
            } else {
                unsigned f;
                do {
                    __builtin_amdgcn_s_sleep(1);
                    f = __hip_atomic_load(&lds_tot[s], __ATOMIC_RELAXED,
                                          __HIP_MEMORY_SCOPE_WORKGROUP);
                } while (f == 0u);
                total = f - 1u;
            }
        }
        total = (unsigned)__shfl((int)total, 0, 64);
        float rate = (float)total / 1843200.0f;  // exact count; one IEEE div = mean
        thr = thr + 0.1f * (rate - 0.1f);
        thr = fminf(fmaxf(thr, 0.1f), 10.0f);
    }
}

extern "C" void kernel_launch(void* const* d_in, const int* in_sizes, int n_in,
                              void* d_out, int out_size, void* d_ws, size_t ws_size,
                              hipStream_t stream) {
    const int*   x = (const int*)d_in[0];
    const int*   y = (const int*)d_in[1];
    const int*   p = (const int*)d_in[2];
    const float* t = (const float*)d_in[3];
    float* out = (float*)d_out;
    const int n = in_sizes[0];

    float* hist = out + (size_t)T_EVT * FRAME;   // steps 10..19 region doubles as hist

    init_kernel<<<1, 64, 0, stream>>>();
    minmax_zero_kernel<<<1024, 256, 0, stream>>>(t, n, (float4*)hist);
    scatter_kernel<<<(n + 255) / 256, 256, 0, stream>>>(x, y, p, t,
                                                        (unsigned*)hist, n);

    dim3 g(NBLK), b(NTHR);
    void* args[] = { (void*)&out };
    hipLaunchCooperativeKernel((void*)scan_kernel, g, b, args, 0, stream);
}

// Round 7
// 438.526 us; speedup vs baseline: 6.8491x; 1.1699x over previous
//
#include <hip/hip_runtime.h>
#include <cstddef>

#define HH 720
#define WW 1280
#define FRAME 1843200            // 2*720*1280
#define FRAME4 460800            // FRAME/4
#define T_EVT 10
#define T_TOTAL 20
#define NBLK 256
#define NTHR 1024
#define NWPB (NTHR / 64)         // 16 waves per block
#define NT (NBLK * NTHR)         // 262144 scan threads
#define NGRP 16                  // arrival-tree fan-in
#define GRPSZ 16                 // blocks per group
#define ARRIVE64 (1ULL << 32)    // arrival token hi32; count lo32

// Persistent device globals for the tiny scalar state.
__device__ unsigned g_minkey;
__device__ unsigned g_maxkey;
// Arrival tree, 128-B padded so every contended word owns its cache line.
__device__ unsigned long long g_grp[T_TOTAL][NGRP][16];  // [s][g][0] used
__device__ unsigned long long g_top[T_TOTAL][16];        // [s][0] used
__device__ unsigned g_rel[T_TOTAL][32];                  // [s][0] used; total+1, 0=not ready

// Monotonic float<->uint key mapping (total order preserved).
__device__ __forceinline__ unsigned f2key(float f) {
    unsigned b = __float_as_uint(f);
    return b ^ ((unsigned)(((int)b) >> 31) | 0x80000000u);
}
__device__ __forceinline__ float key2f(unsigned k) {
    unsigned b = (k & 0x80000000u) ? (k ^ 0x80000000u) : ~k;
    return __uint_as_float(b);
}

__global__ void init_kernel() {
    const int gtid = blockIdx.x * blockDim.x + threadIdx.x;
    if (gtid == 0) { g_minkey = 0xFFFFFFFFu; g_maxkey = 0u; }
    // zero the whole tree (padding included: simplest correct form)
    unsigned long long* grp = &g_grp[0][0][0];
    for (int i = gtid; i < T_TOTAL * NGRP * 16; i += gridDim.x * blockDim.x) grp[i] = 0ull;
    unsigned long long* top = &g_top[0][0];
    for (int i = gtid; i < T_TOTAL * 16; i += gridDim.x * blockDim.x) top[i] = 0ull;
    unsigned* rel = &g_rel[0][0];
    for (int i = gtid; i < T_TOTAL * 32; i += gridDim.x * blockDim.x) rel[i] = 0u;
}

// min/max of t (float4-vectorized), fused with zeroing the histogram region.
// Kernel boundary before scatter_kernel guarantees both complete + coherent.
__global__ void minmax_zero_kernel(const float* __restrict__ t, int n,
                                   float4* __restrict__ hist4) {
    const int gtid = blockIdx.x * blockDim.x + threadIdx.x;
    const int gstride = gridDim.x * blockDim.x;

    const float4 z = make_float4(0.f, 0.f, 0.f, 0.f);
    for (int i = gtid; i < T_EVT * FRAME4; i += gstride) hist4[i] = z;

    unsigned mn = 0xFFFFFFFFu, mx = 0u;
    const int n4 = n >> 2;
    const float4* t4 = (const float4*)t;
    for (int i = gtid; i < n4; i += gstride) {
        float4 tv = t4[i];
        unsigned k0 = f2key(tv.x), k1 = f2key(tv.y);
        unsigned k2 = f2key(tv.z), k3 = f2key(tv.w);
        unsigned a = k0 < k1 ? k0 : k1, b = k2 < k3 ? k2 : k3;
        unsigned c = a < b ? a : b;
        mn = mn < c ? mn : c;
        a = k0 > k1 ? k0 : k1; b = k2 > k3 ? k2 : k3;
        c = a > b ? a : b;
        mx = mx > c ? mx : c;
    }
    for (int i = (n4 << 2) + gtid; i < n; i += gstride) {  // tail
        unsigned k = f2key(t[i]);
        mn = mn < k ? mn : k;
        mx = mx > k ? mx : k;
    }
    for (int off = 32; off > 0; off >>= 1) {
        unsigned omn = (unsigned)__shfl_down((int)mn, off, 64);
        unsigned omx = (unsigned)__shfl_down((int)mx, off, 64);
        mn = mn < omn ? mn : omn;
        mx = mx > omx ? mx : omx;
    }
    __shared__ unsigned smn[16], smx[16];
    int lane = threadIdx.x & 63, wv = threadIdx.x >> 6;
    if (lane == 0) { smn[wv] = mn; smx[wv] = mx; }
    __syncthreads();
    if (threadIdx.x == 0) {
        int nw = blockDim.x >> 6;
        for (int i = 1; i < nw; ++i) {
            mn = mn < smn[i] ? mn : smn[i];
            mx = mx > smx[i] ? mx : smx[i];
        }
        atomicMin(&g_minkey, mn);
        atomicMax(&g_maxkey, mx);
    }
}

// 1 event/thread, u32 atomics on the count grid (integer RMW > fp32 RMW at L2;
// scan converts u32->f32 at load, bit-exact vs fp32 +1.0 accumulation).
__global__ void scatter_kernel(const int* __restrict__ x, const int* __restrict__ y,
                               const int* __restrict__ p, const float* __restrict__ t,
                               unsigned* __restrict__ hist, int n) {
#pragma clang fp contract(off)
    int i = blockIdx.x * blockDim.x + threadIdx.x;
    if (i >= n) return;
    float tmin = key2f(g_minkey);
    float tmax = key2f(g_maxkey);
    float tv = t[i];
    float tn;
    if (tmax > tmin) {
        // exact reference op order: ((t - tmin) / denom) * (10 - 1e-6), fp32 IEEE
        tn = (tv - tmin) / (tmax - tmin) * (float)(10.0 - 1e-6);
    } else {
        tn = 0.0f;
    }
    int ti = (int)tn;                     // trunc toward zero, tn >= 0
    ti = ti < 0 ? 0 : (ti > T_EVT - 1 ? T_EVT - 1 : ti);
    int xi = x[i]; xi = xi < 0 ? 0 : (xi > WW - 1 ? WW - 1 : xi);
    int yi = y[i]; yi = yi < 0 ? 0 : (yi > HH - 1 ? HH - 1 : yi);
    int ci = p[i];                        // p in {0,1}, used directly per reference
    size_t off = (size_t)ti * FRAME + (size_t)ci * (HH * WW) + (size_t)yi * WW + xi;
    atomicAdd(hist + off, 1u);
}

// Cooperative scan. Barrier = contention-free arrival TREE + write-once release:
//   wave shuffle-reduce -> per-wave LDS packed atomic -> block-last wave adds
//   (count,arrive) to its GROUP line (16 adds/line, lines 128-B padded) ->
//   group-last forwards to TOP line (16 adds) -> top-last stores total+1 to a
//   separate release word. All 256 block leaders spin READ-ONLY on the release
//   word (no RMW/reader ping-pong), then publish block-locally via LDS.
//   R5 calibration: same-line op ~33 ns; R6's 256 ops/step = 8.4 us/step. The
//   tree caps any line at 16 RMWs and the release line at reads only.
// hist frames live in out[(10+s)*FRAME]; step 10+s overwrites that region at
// the SAME per-thread indices -> same-lane same-address ordering suffices.
__global__ __launch_bounds__(NTHR) void scan_kernel(float* __restrict__ out) {
#pragma clang fp contract(off)
    const float decay = (float)0.9048374180359595;  // float32(exp(-1/10))
    const int gtid = blockIdx.x * NTHR + threadIdx.x;
    const int lane = threadIdx.x & 63;
    const uint4 uz = make_uint4(0u, 0u, 0u, 0u);

    float4 mem0 = make_float4(0.f, 0.f, 0.f, 0.f);
    float4 mem1 = make_float4(0.f, 0.f, 0.f, 0.f);
    const bool has1 = (gtid + NT) < FRAME4;   // k=0 always valid (NT <= FRAME4)
    float thr = 1.0f;

    __shared__ unsigned lds_arr[T_TOTAL];   // per-step: count lo16 | arrivals<<16
    __shared__ unsigned lds_tot[T_TOTAL];   // per-step: global total + 1 (0 = not ready)
    if (threadIdx.x < T_TOTAL) { lds_arr[threadIdx.x] = 0u; lds_tot[threadIdx.x] = 0u; }
    __syncthreads();   // once, outside the loop

    // preload step 0's frame as raw uint counts
    uint4 u0, u1;
    {
        const uint4* h = (const uint4*)(out + (size_t)T_EVT * FRAME);
        u0 = h[gtid];
        u1 = has1 ? h[gtid + NT] : uz;
    }

    for (int s = 0; s < T_TOTAL; ++s) {
        float4* o4 = (float4*)(out + (size_t)s * FRAME);
        int cnt = 0;

        {   // k = 0  (u->f conversion here, after the previous step's wait)
            float4 m, spk;
            m.x = mem0.x * decay; m.x = m.x + (float)u0.x;
            m.y = mem0.y * decay; m.y = m.y + (float)u0.y;
            m.z = mem0.z * decay; m.z = m.z + (float)u0.z;
            m.w = mem0.w * decay; m.w = m.w + (float)u0.w;
            spk.x = (m.x >= thr) ? 1.0f : 0.0f;
            spk.y = (m.y >= thr) ? 1.0f : 0.0f;
            spk.z = (m.z >= thr) ? 1.0f : 0.0f;
            spk.w = (m.w >= thr) ? 1.0f : 0.0f;
            o4[gtid] = spk;
            mem0.x = m.x - spk.x * thr;
            mem0.y = m.y - spk.y * thr;
            mem0.z = m.z - spk.z * thr;
            mem0.w = m.w - spk.w * thr;
            cnt += (int)spk.x + (int)spk.y + (int)spk.z + (int)spk.w;
        }
        if (has1) {   // k = 1
            float4 m, spk;
            m.x = mem1.x * decay; m.x = m.x + (float)u1.x;
            m.y = mem1.y * decay; m.y = m.y + (float)u1.y;
            m.z = mem1.z * decay; m.z = m.z + (float)u1.z;
            m.w = mem1.w * decay; m.w = m.w + (float)u1.w;
            spk.x = (m.x >= thr) ? 1.0f : 0.0f;
            spk.y = (m.y >= thr) ? 1.0f : 0.0f;
            spk.z = (m.z >= thr) ? 1.0f : 0.0f;
            spk.w = (m.w >= thr) ? 1.0f : 0.0f;
            o4[gtid + NT] = spk;
            mem1.x = m.x - spk.x * thr;
            mem1.y = m.y - spk.y * thr;
            mem1.z = m.z - spk.z * thr;
            mem1.w = m.w - spk.w * thr;
            cnt += (int)spk.x + (int)spk.y + (int)spk.z + (int)spk.w;
        }

        // prefetch step s+1's frame (raw uint4; stays in flight through the wait)
        if (s + 1 < T_EVT) {
            const uint4* hn = (const uint4*)(out + (size_t)(T_EVT + s + 1) * FRAME);
            u0 = hn[gtid];
            u1 = has1 ? hn[gtid + NT] : uz;
        } else {
            u0 = uz; u1 = uz;
        }

        if (s == T_TOTAL - 1) break;   // last step's count is never consumed

        for (int off = 32; off > 0; off >>= 1) cnt += __shfl_down(cnt, off, 64);
        unsigned total;
        if (lane == 0) {
            unsigned old = __hip_atomic_fetch_add(&lds_arr[s],
                               (unsigned)cnt + (1u << 16),
                               __ATOMIC_RELAXED, __HIP_MEMORY_SCOPE_WORKGROUP);
            if ((old >> 16) == NWPB - 1) {
                // last wave of this block: climb the arrival tree
                unsigned blockcnt = (old + (unsigned)cnt) & 0xFFFFu;
                const int gid = blockIdx.x >> 4;   // 16 groups of 16 blocks
                unsigned long long gold = __hip_atomic_fetch_add(
                    &g_grp[s][gid][0], (unsigned long long)blockcnt + ARRIVE64,
                    __ATOMIC_RELAXED, __HIP_MEMORY_SCOPE_AGENT);
                if ((unsigned)(gold >> 32) == GRPSZ - 1) {
                    unsigned gcnt = (unsigned)gold + blockcnt;
                    unsigned long long told = __hip_atomic_fetch_add(
                        &g_top[s][0], (unsigned long long)gcnt + ARRIVE64,
                        __ATOMIC_RELAXED, __HIP_MEMORY_SCOPE_AGENT);
                    if ((unsigned)(told >> 32) == NGRP - 1) {
                        unsigned tot = (unsigned)told + gcnt;
                        __hip_atomic_store(&g_rel[s][0], tot + 1u,
                                           __ATOMIC_RELAXED, __HIP_MEMORY_SCOPE_AGENT);
                    }
                }
                // read-only spin on the release word
                unsigned f;
                do {
                    __builtin_amdgcn_s_sleep(1);
                    f = __hip_atomic_load(&g_rel[s][0], __ATOMIC_RELAXED,
                                          __HIP_MEMORY_SCOPE_AGENT);
                } while (f == 0u);
                total = f - 1u;
                __hip_atomic_store(&lds_tot[s], f,
                                   __ATOMIC_RELAXED, __HIP_MEMORY_SCOPE_WORKGROUP);
            } else {
                unsigned f;
                do {
                    __builtin_amdgcn_s_sleep(1);
                    f = __hip_atomic_load(&lds_tot[s], __ATOMIC_RELAXED,
                                          __HIP_MEMORY_SCOPE_WORKGROUP);
                } while (f == 0u);
                total = f - 1u;
            }
        }
        total = (unsigned)__shfl((int)total, 0, 64);
        float rate = (float)total / 1843200.0f;  // exact count; one IEEE div = mean
        thr = thr + 0.1f * (rate - 0.1f);
        thr = fminf(fmaxf(thr, 0.1f), 10.0f);
    }
}

extern "C" void kernel_launch(void* const* d_in, const int* in_sizes, int n_in,
                              void* d_out, int out_size, void* d_ws, size_t ws_size,
                              hipStream_t stream) {
    const int*   x = (const int*)d_in[0];
    const int*   y = (const int*)d_in[1];
    const int*   p = (const int*)d_in[2];
    const float* t = (const float*)d_in[3];
    float* out = (float*)d_out;
    const int n = in_sizes[0];

    float* hist = out + (size_t)T_EVT * FRAME;   // steps 10..19 region doubles as hist

    init_kernel<<<16, 256, 0, stream>>>();
    minmax_zero_kernel<<<1024, 256, 0, stream>>>(t, n, (float4*)hist);
    scatter_kernel<<<(n + 255) / 256, 256, 0, stream>>>(x, y, p, t,
                                                        (unsigned*)hist, n);

    dim3 g(NBLK), b(NTHR);
    void* args[] = { (void*)&out };
    hipLaunchCooperativeKernel((void*)scan_kernel, g, b, args, 0, stream);
}

// Round 8
// 425.303 us; speedup vs baseline: 7.0620x; 1.0311x over previous
//
#include <hip/hip_runtime.h>
#include <cstddef>

#define HH 720
#define WW 1280
#define FRAME 1843200            // 2*720*1280
#define FRAME4 460800            // FRAME/4
#define T_EVT 10
#define T_TOTAL 20
#define NBLK 256
#define NTHR 1024
#define NWPB (NTHR / 64)         // 16 waves per block
#define NT (NBLK * NTHR)         // 262144 scan threads
#define NGRP 16                  // arrival-tree fan-in
#define GRPSZ 16                 // blocks per group
#define ARRIVE64 (1ULL << 32)    // arrival token hi32; count lo32

// Persistent device globals for the tiny scalar state.
__device__ unsigned g_minkey;
__device__ unsigned g_maxkey;
// Arrival tree, 128-B padded so every contended word owns its cache line.
__device__ unsigned long long g_grp[T_TOTAL][NGRP][16];  // [s][g][0] used
__device__ unsigned long long g_top[T_TOTAL][16];        // [s][0] used
__device__ unsigned g_rel[T_TOTAL][32];                  // [s][0] used; total+1, 0=not ready

// Monotonic float<->uint key mapping (total order preserved).
__device__ __forceinline__ unsigned f2key(float f) {
    unsigned b = __float_as_uint(f);
    return b ^ ((unsigned)(((int)b) >> 31) | 0x80000000u);
}
__device__ __forceinline__ float key2f(unsigned k) {
    unsigned b = (k & 0x80000000u) ? (k ^ 0x80000000u) : ~k;
    return __uint_as_float(b);
}

__global__ void init_kernel() {
    const int gtid = blockIdx.x * blockDim.x + threadIdx.x;
    if (gtid == 0) { g_minkey = 0xFFFFFFFFu; g_maxkey = 0u; }
    unsigned long long* grp = &g_grp[0][0][0];
    for (int i = gtid; i < T_TOTAL * NGRP * 16; i += gridDim.x * blockDim.x) grp[i] = 0ull;
    unsigned long long* top = &g_top[0][0];
    for (int i = gtid; i < T_TOTAL * 16; i += gridDim.x * blockDim.x) top[i] = 0ull;
    unsigned* rel = &g_rel[0][0];
    for (int i = gtid; i < T_TOTAL * 32; i += gridDim.x * blockDim.x) rel[i] = 0u;
}

// min/max of t (float4-vectorized), fused with zeroing the u16 histogram
// region (36.9 MB). Kernel boundary before scatter guarantees completion.
__global__ void minmax_zero_kernel(const float* __restrict__ t, int n,
                                   uint4* __restrict__ hist16v) {
    const int gtid = blockIdx.x * blockDim.x + threadIdx.x;
    const int gstride = gridDim.x * blockDim.x;

    const uint4 z = make_uint4(0u, 0u, 0u, 0u);
    const int nz = T_EVT * FRAME / 8;   // u16 hist = 36.9 MB = 2,304,000 uint4
    for (int i = gtid; i < nz; i += gstride) hist16v[i] = z;

    unsigned mn = 0xFFFFFFFFu, mx = 0u;
    const int n4 = n >> 2;
    const float4* t4 = (const float4*)t;
    for (int i = gtid; i < n4; i += gstride) {
        float4 tv = t4[i];
        unsigned k0 = f2key(tv.x), k1 = f2key(tv.y);
        unsigned k2 = f2key(tv.z), k3 = f2key(tv.w);
        unsigned a = k0 < k1 ? k0 : k1, b = k2 < k3 ? k2 : k3;
        unsigned c = a < b ? a : b;
        mn = mn < c ? mn : c;
        a = k0 > k1 ? k0 : k1; b = k2 > k3 ? k2 : k3;
        c = a > b ? a : b;
        mx = mx > c ? mx : c;
    }
    for (int i = (n4 << 2) + gtid; i < n; i += gstride) {  // tail
        unsigned k = f2key(t[i]);
        mn = mn < k ? mn : k;
        mx = mx > k ? mx : k;
    }
    for (int off = 32; off > 0; off >>= 1) {
        unsigned omn = (unsigned)__shfl_down((int)mn, off, 64);
        unsigned omx = (unsigned)__shfl_down((int)mx, off, 64);
        mn = mn < omn ? mn : omn;
        mx = mx > omx ? mx : omx;
    }
    __shared__ unsigned smn[16], smx[16];
    int lane = threadIdx.x & 63, wv = threadIdx.x >> 6;
    if (lane == 0) { smn[wv] = mn; smx[wv] = mx; }
    __syncthreads();
    if (threadIdx.x == 0) {
        int nw = blockDim.x >> 6;
        for (int i = 1; i < nw; ++i) {
            mn = mn < smn[i] ? mn : smn[i];
            mx = mx > smx[i] ? mx : smx[i];
        }
        atomicMin(&g_minkey, mn);
        atomicMax(&g_maxkey, mx);
    }
}

// 1 event/thread, u16-packed hist: atomicAdd(word, 1<<((bin&1)*16)).
// Counts <= ~10 (Poisson lambda 0.22) -> no u16 overflow, no carry pollution.
// Halves distinct dirty lines vs u32 hist -> ~half the write-back traffic.
__global__ void scatter_kernel(const int* __restrict__ x, const int* __restrict__ y,
                               const int* __restrict__ p, const float* __restrict__ t,
                               unsigned* __restrict__ hist32, int n) {
#pragma clang fp contract(off)
    int i = blockIdx.x * blockDim.x + threadIdx.x;
    if (i >= n) return;
    float tmin = key2f(g_minkey);
    float tmax = key2f(g_maxkey);
    float tv = t[i];
    float tn;
    if (tmax > tmin) {
        // exact reference op order: ((t - tmin) / denom) * (10 - 1e-6), fp32 IEEE
        tn = (tv - tmin) / (tmax - tmin) * (float)(10.0 - 1e-6);
    } else {
        tn = 0.0f;
    }
    int ti = (int)tn;                     // trunc toward zero, tn >= 0
    ti = ti < 0 ? 0 : (ti > T_EVT - 1 ? T_EVT - 1 : ti);
    int xi = x[i]; xi = xi < 0 ? 0 : (xi > WW - 1 ? WW - 1 : xi);
    int yi = y[i]; yi = yi < 0 ? 0 : (yi > HH - 1 ? HH - 1 : yi);
    int ci = p[i];                        // p in {0,1}, used directly per reference
    size_t b = (size_t)ti * FRAME + (size_t)ci * (HH * WW) + (size_t)yi * WW + xi;
    atomicAdd(hist32 + (b >> 1), 1u << ((b & 1) << 4));
}

// Cooperative scan (R7 tree barrier, unchanged). u16 hist: two uint2 loads per
// thread per step; (float)(v&0xFFFF) unpack is bit-exact. All hist reads occur
// at steps 0..9; spike writes to the tail region [10F,20F) occur only at steps
// 10..19 -> any hist placement in the tail is race-free.
__global__ __launch_bounds__(NTHR) void scan_kernel(float* __restrict__ out) {
#pragma clang fp contract(off)
    const float decay = (float)0.9048374180359595;  // float32(exp(-1/10))
    const int gtid = blockIdx.x * NTHR + threadIdx.x;
    const int lane = threadIdx.x & 63;
    const uint2 uz2 = make_uint2(0u, 0u);

    float4 mem0 = make_float4(0.f, 0.f, 0.f, 0.f);
    float4 mem1 = make_float4(0.f, 0.f, 0.f, 0.f);
    const bool has1 = (gtid + NT) < FRAME4;   // k=0 always valid (NT <= FRAME4)
    float thr = 1.0f;

    const uint2* hist2 = (const uint2*)(out + (size_t)T_EVT * FRAME);
    // frame s for this thread: uint2 index s*FRAME4 + gtid (4 u16 counts)

    __shared__ unsigned lds_arr[T_TOTAL];   // per-step: count lo16 | arrivals<<16
    __shared__ unsigned lds_tot[T_TOTAL];   // per-step: global total + 1 (0 = not ready)
    if (threadIdx.x < T_TOTAL) { lds_arr[threadIdx.x] = 0u; lds_tot[threadIdx.x] = 0u; }
    __syncthreads();   // once, outside the loop

    // preload step 0's frame as packed u16 counts
    uint2 u0 = hist2[gtid];
    uint2 u1 = has1 ? hist2[gtid + NT] : uz2;

    for (int s = 0; s < T_TOTAL; ++s) {
        float4* o4 = (float4*)(out + (size_t)s * FRAME);
        int cnt = 0;

        {   // k = 0  (unpack here, after the previous step's wait)
            float4 m, spk;
            m.x = mem0.x * decay; m.x = m.x + (float)(u0.x & 0xFFFFu);
            m.y = mem0.y * decay; m.y = m.y + (float)(u0.x >> 16);
            m.z = mem0.z * decay; m.z = m.z + (float)(u0.y & 0xFFFFu);
            m.w = mem0.w * decay; m.w = m.w + (float)(u0.y >> 16);
            spk.x = (m.x >= thr) ? 1.0f : 0.0f;
            spk.y = (m.y >= thr) ? 1.0f : 0.0f;
            spk.z = (m.z >= thr) ? 1.0f : 0.0f;
            spk.w = (m.w >= thr) ? 1.0f : 0.0f;
            o4[gtid] = spk;
            mem0.x = m.x - spk.x * thr;
            mem0.y = m.y - spk.y * thr;
            mem0.z = m.z - spk.z * thr;
            mem0.w = m.w - spk.w * thr;
            cnt += (int)spk.x + (int)spk.y + (int)spk.z + (int)spk.w;
        }
        if (has1) {   // k = 1
            float4 m, spk;
            m.x = mem1.x * decay; m.x = m.x + (float)(u1.x & 0xFFFFu);
            m.y = mem1.y * decay; m.y = m.y + (float)(u1.x >> 16);
            m.z = mem1.z * decay; m.z = m.z + (float)(u1.y & 0xFFFFu);
            m.w = mem1.w * decay; m.w = m.w + (float)(u1.y >> 16);
            spk.x = (m.x >= thr) ? 1.0f : 0.0f;
            spk.y = (m.y >= thr) ? 1.0f : 0.0f;
            spk.z = (m.z >= thr) ? 1.0f : 0.0f;
            spk.w = (m.w >= thr) ? 1.0f : 0.0f;
            o4[gtid + NT] = spk;
            mem1.x = m.x - spk.x * thr;
            mem1.y = m.y - spk.y * thr;
            mem1.z = m.z - spk.z * thr;
            mem1.w = m.w - spk.w * thr;
            cnt += (int)spk.x + (int)spk.y + (int)spk.z + (int)spk.w;
        }

        // prefetch step s+1's frame (raw uint2; stays in flight through the wait)
        if (s + 1 < T_EVT) {
            const uint2* hn = hist2 + (size_t)(s + 1) * FRAME4;
            u0 = hn[gtid];
            u1 = has1 ? hn[gtid + NT] : uz2;
        } else {
            u0 = uz2; u1 = uz2;
        }

        if (s == T_TOTAL - 1) break;   // last step's count is never consumed

        for (int off = 32; off > 0; off >>= 1) cnt += __shfl_down(cnt, off, 64);
        unsigned total;
        if (lane == 0) {
            unsigned old = __hip_atomic_fetch_add(&lds_arr[s],
                               (unsigned)cnt + (1u << 16),
                               __ATOMIC_RELAXED, __HIP_MEMORY_SCOPE_WORKGROUP);
            if ((old >> 16) == NWPB - 1) {
                // last wave of this block: climb the arrival tree
                unsigned blockcnt = (old + (unsigned)cnt) & 0xFFFFu;
                const int gid = blockIdx.x >> 4;   // 16 groups of 16 blocks
                unsigned long long gold = __hip_atomic_fetch_add(
                    &g_grp[s][gid][0], (unsigned long long)blockcnt + ARRIVE64,
                    __ATOMIC_RELAXED, __HIP_MEMORY_SCOPE_AGENT);
                if ((unsigned)(gold >> 32) == GRPSZ - 1) {
                    unsigned gcnt = (unsigned)gold + blockcnt;
                    unsigned long long told = __hip_atomic_fetch_add(
                        &g_top[s][0], (unsigned long long)gcnt + ARRIVE64,
                        __ATOMIC_RELAXED, __HIP_MEMORY_SCOPE_AGENT);
                    if ((unsigned)(told >> 32) == NGRP - 1) {
                        unsigned tot = (unsigned)told + gcnt;
                        __hip_atomic_store(&g_rel[s][0], tot + 1u,
                                           __ATOMIC_RELAXED, __HIP_MEMORY_SCOPE_AGENT);
                    }
                }
                // read-only spin on the release word
                unsigned f;
                do {
                    __builtin_amdgcn_s_sleep(1);
                    f = __hip_atomic_load(&g_rel[s][0], __ATOMIC_RELAXED,
                                          __HIP_MEMORY_SCOPE_AGENT);
                } while (f == 0u);
                total = f - 1u;
                __hip_atomic_store(&lds_tot[s], f,
                                   __ATOMIC_RELAXED, __HIP_MEMORY_SCOPE_WORKGROUP);
            } else {
                unsigned f;
                do {
                    __builtin_amdgcn_s_sleep(1);
                    f = __hip_atomic_load(&lds_tot[s], __ATOMIC_RELAXED,
                                          __HIP_MEMORY_SCOPE_WORKGROUP);
                } while (f == 0u);
                total = f - 1u;
            }
        }
        total = (unsigned)__shfl((int)total, 0, 64);
        float rate = (float)total / 1843200.0f;  // exact count; one IEEE div = mean
        thr = thr + 0.1f * (rate - 0.1f);
        thr = fminf(fmaxf(thr, 0.1f), 10.0f);
    }
}

extern "C" void kernel_launch(void* const* d_in, const int* in_sizes, int n_in,
                              void* d_out, int out_size, void* d_ws, size_t ws_size,
                              hipStream_t stream) {
    const int*   x = (const int*)d_in[0];
    const int*   y = (const int*)d_in[1];
    const int*   p = (const int*)d_in[2];
    const float* t = (const float*)d_in[3];
    float* out = (float*)d_out;
    const int n = in_sizes[0];

    // u16 hist (36.9 MB) lives at the start of the tail region [10F..20F)
    unsigned* hist32 = (unsigned*)(out + (size_t)T_EVT * FRAME);

    init_kernel<<<16, 256, 0, stream>>>();
    minmax_zero_kernel<<<1024, 256, 0, stream>>>(t, n, (uint4*)hist32);
    scatter_kernel<<<(n + 255) / 256, 256, 0, stream>>>(x, y, p, t, hist32, n);

    dim3 g(NBLK), b(NTHR);
    void* args[] = { (void*)&out };
    hipLaunchCooperativeKernel((void*)scan_kernel, g, b, args, 0, stream);
}

// Round 9
// 415.036 us; speedup vs baseline: 7.2367x; 1.0247x over previous
//
#include <hip/hip_runtime.h>
#include <cstddef>

#define HH 720
#define WW 1280
#define FRAME 1843200            // 2*720*1280
#define FRAME4 460800            // FRAME/4
#define T_EVT 10
#define T_TOTAL 20
#define ARRIVE64 (1ULL << 32)

// ---------- old (fallback) path config ----------
#define ONBLK 256
#define ONTHR 1024
#define ONWPB 16
#define ONT (ONBLK * ONTHR)

// ---------- new path config ----------
#define SBLK 1024                // scan blocks (4 per CU)
#define STHR 256                 // scan threads per block (4 waves)
#define SWPB 4
#define PIXB 1800                // pixels per scan block
#define NGROUP4 450              // float4 groups per block (1800/4)
#define HIST_W 9000              // LDS hist words (18000 u16)
#define RBLK 256                 // passA/passB blocks
#define NBUCKET 1024

// ws layout (bytes)
#define MAT_OFF   0u                          // u32[256*1024] = 1 MB
#define SB_OFF    (256u * 1024u * 4u)         // u32[1025]
#define SEG_OFF   (SB_OFF + 8192u)            // u16[n]
#define WS_NEED(n) ((size_t)SEG_OFF + 2ull * (size_t)(n) + 256ull)

// Persistent device globals.
__device__ unsigned g_minkey;
__device__ unsigned g_maxkey;
// old-path tree (R8, proven)
__device__ unsigned long long g_grp[T_TOTAL][16][16];
__device__ unsigned long long g_top[T_TOTAL][16];
__device__ unsigned g_rel[T_TOTAL][32];
// new-path tree: 1024 -> 64 -> 4 -> 1, then fan-out to 64 group-release words
__device__ unsigned long long g_n1[T_TOTAL][64][16];
__device__ unsigned long long g_n2[T_TOTAL][4][16];
__device__ unsigned long long g_n3[T_TOTAL][16];
__device__ unsigned g_relg[T_TOTAL][64][32];   // [s][group][0]: total+1

__device__ __forceinline__ unsigned f2key(float f) {
    unsigned b = __float_as_uint(f);
    return b ^ ((unsigned)(((int)b) >> 31) | 0x80000000u);
}
__device__ __forceinline__ float key2f(unsigned k) {
    unsigned b = (k & 0x80000000u) ? (k ^ 0x80000000u) : ~k;
    return __uint_as_float(b);
}

// Exact reference bin: ((t-tmin)/(tmax-tmin))*(10-1e-6), trunc, clip. Shared by
// old scatter and new passA/passB so all agree bit-exactly.
__device__ __forceinline__ int event_bin_t(float tv, float tmin, float tmax) {
#pragma clang fp contract(off)
    float tn;
    if (tmax > tmin) tn = (tv - tmin) / (tmax - tmin) * (float)(10.0 - 1e-6);
    else tn = 0.0f;
    int ti = (int)tn;
    return ti < 0 ? 0 : (ti > T_EVT - 1 ? T_EVT - 1 : ti);
}
__device__ __forceinline__ int event_pixel(int xi, int yi, int ci) {
    xi = xi < 0 ? 0 : (xi > WW - 1 ? WW - 1 : xi);
    yi = yi < 0 ? 0 : (yi > HH - 1 ? HH - 1 : yi);
    return ci * (HH * WW) + yi * WW + xi;
}

__global__ void init_kernel() {
    const int gtid = blockIdx.x * blockDim.x + threadIdx.x;
    const int gs = gridDim.x * blockDim.x;
    if (gtid == 0) { g_minkey = 0xFFFFFFFFu; g_maxkey = 0u; }
    unsigned long long* a = &g_grp[0][0][0];
    for (int i = gtid; i < T_TOTAL * 16 * 16; i += gs) a[i] = 0ull;
    unsigned long long* b = &g_top[0][0];
    for (int i = gtid; i < T_TOTAL * 16; i += gs) b[i] = 0ull;
    unsigned* c = &g_rel[0][0];
    for (int i = gtid; i < T_TOTAL * 32; i += gs) c[i] = 0u;
    unsigned long long* d = &g_n1[0][0][0];
    for (int i = gtid; i < T_TOTAL * 64 * 16; i += gs) d[i] = 0ull;
    unsigned long long* e = &g_n2[0][0][0];
    for (int i = gtid; i < T_TOTAL * 4 * 16; i += gs) e[i] = 0ull;
    unsigned long long* f = &g_n3[0][0];
    for (int i = gtid; i < T_TOTAL * 16; i += gs) f[i] = 0ull;
    unsigned* g = &g_relg[0][0][0];
    for (int i = gtid; i < T_TOTAL * 64 * 32; i += gs) g[i] = 0u;
}

// ======================= shared: t min/max =======================
__device__ __forceinline__ void minmax_body(const float* __restrict__ t, int n,
                                            int gtid, int gstride) {
    unsigned mn = 0xFFFFFFFFu, mx = 0u;
    const int n4 = n >> 2;
    const float4* t4 = (const float4*)t;
    for (int i = gtid; i < n4; i += gstride) {
        float4 tv = t4[i];
        unsigned k0 = f2key(tv.x), k1 = f2key(tv.y);
        unsigned k2 = f2key(tv.z), k3 = f2key(tv.w);
        unsigned a = k0 < k1 ? k0 : k1, b = k2 < k3 ? k2 : k3;
        unsigned c = a < b ? a : b;
        mn = mn < c ? mn : c;
        a = k0 > k1 ? k0 : k1; b = k2 > k3 ? k2 : k3;
        c = a > b ? a : b;
        mx = mx > c ? mx : c;
    }
    for (int i = (n4 << 2) + gtid; i < n; i += gstride) {
        unsigned k = f2key(t[i]);
        mn = mn < k ? mn : k;
        mx = mx > k ? mx : k;
    }
    for (int off = 32; off > 0; off >>= 1) {
        unsigned omn = (unsigned)__shfl_down((int)mn, off, 64);
        unsigned omx = (unsigned)__shfl_down((int)mx, off, 64);
        mn = mn < omn ? mn : omn;
        mx = mx > omx ? mx : omx;
    }
    __shared__ unsigned smn[16], smx[16];
    int lane = threadIdx.x & 63, wv = threadIdx.x >> 6;
    if (lane == 0) { smn[wv] = mn; smx[wv] = mx; }
    __syncthreads();
    if (threadIdx.x == 0) {
        int nw = blockDim.x >> 6;
        for (int i = 1; i < nw; ++i) {
            mn = mn < smn[i] ? mn : smn[i];
            mx = mx > smx[i] ? mx : smx[i];
        }
        atomicMin(&g_minkey, mn);
        atomicMax(&g_maxkey, mx);
    }
}

__global__ void minmax_kernel(const float* __restrict__ t, int n) {
    minmax_body(t, n, blockIdx.x * blockDim.x + threadIdx.x,
                gridDim.x * blockDim.x);
}

// old fallback: minmax fused with zeroing out-tail u16 hist
__global__ void minmax_zero_kernel(const float* __restrict__ t, int n,
                                   uint4* __restrict__ hist16v) {
    const int gtid = blockIdx.x * blockDim.x + threadIdx.x;
    const int gstride = gridDim.x * blockDim.x;
    const uint4 z = make_uint4(0u, 0u, 0u, 0u);
    const int nz = T_EVT * FRAME / 8;
    for (int i = gtid; i < nz; i += gstride) hist16v[i] = z;
    minmax_body(t, n, gtid, gstride);
}

// ======================= new path: counting sort =======================
__global__ void passA_kernel(const int* __restrict__ x, const int* __restrict__ y,
                             const int* __restrict__ p, const float* __restrict__ t,
                             unsigned* __restrict__ mat, int n) {
    __shared__ unsigned cnt[NBUCKET];
    for (int i = threadIdx.x; i < NBUCKET; i += blockDim.x) cnt[i] = 0u;
    __syncthreads();
    const int chunk = (n + (int)gridDim.x - 1) / (int)gridDim.x;
    const int s0 = blockIdx.x * chunk;
    const int s1 = min(n, s0 + chunk);
    for (int i = s0 + threadIdx.x; i < s1; i += blockDim.x) {
        int pix = event_pixel(x[i], y[i], p[i]);
        atomicAdd(&cnt[pix / PIXB], 1u);
    }
    __syncthreads();
    for (int i = threadIdx.x; i < NBUCKET; i += blockDim.x)
        mat[blockIdx.x * NBUCKET + i] = cnt[i];
}

// single block, NBUCKET threads: column exclusive scan (in place) + seg bases
__global__ void offsets_kernel(unsigned* __restrict__ mat,
                               unsigned* __restrict__ seg_base, int n) {
    __shared__ unsigned bt[NBUCKET];
    __shared__ unsigned sb[NBUCKET];
    const int j = threadIdx.x;
    unsigned run = 0;
    for (int r = 0; r < RBLK; ++r) {
        unsigned v = mat[r * NBUCKET + j];
        mat[r * NBUCKET + j] = run;
        run += v;
    }
    bt[j] = run;
    __syncthreads();
    if (j == 0) {
        unsigned s = 0;
        for (int k = 0; k < NBUCKET; ++k) { sb[k] = s; s += bt[k]; }
        seg_base[NBUCKET] = s;   // == n
    }
    __syncthreads();
    seg_base[j] = sb[j];
}

__global__ void passB_kernel(const int* __restrict__ x, const int* __restrict__ y,
                             const int* __restrict__ p, const float* __restrict__ t,
                             const unsigned* __restrict__ mat,
                             const unsigned* __restrict__ seg_base,
                             unsigned short* __restrict__ seg, int n) {
    __shared__ unsigned base[NBUCKET];
    for (int i = threadIdx.x; i < NBUCKET; i += blockDim.x)
        base[i] = mat[blockIdx.x * NBUCKET + i] + seg_base[i];
    __syncthreads();
    const float tmin = key2f(g_minkey);
    const float tmax = key2f(g_maxkey);
    const int chunk = (n + (int)gridDim.x - 1) / (int)gridDim.x;
    const int s0 = blockIdx.x * chunk;
    const int s1 = min(n, s0 + chunk);
    for (int i = s0 + threadIdx.x; i < s1; i += blockDim.x) {
        int pix = event_pixel(x[i], y[i], p[i]);
        int ti = event_bin_t(t[i], tmin, tmax);
        int bkt = pix / PIXB;
        int lb = ti * PIXB + (pix - bkt * PIXB);   // < 18000
        unsigned idx = atomicAdd(&base[bkt], 1u);
        seg[idx] = (unsigned short)lb;
    }
}

// Cooperative scan, 1024 blocks x 256 thr, per-block 36 KB LDS hist.
// Block b owns pixels [b*1800, b*1800+1800) for all 20 steps; hist counts come
// from its ws segment via LDS atomics (no global hist at all). Barrier: 3-level
// arrival tree (1024->64->4->1), counts ride the payloads; top-last fans out
// total+1 to 64 group-release words; <=16 read-only spinners per word.
__global__ __launch_bounds__(STHR, 4) void scan_new(float* __restrict__ out,
                                                    const unsigned short* __restrict__ seg,
                                                    const unsigned* __restrict__ seg_base) {
#pragma clang fp contract(off)
    const float decay = (float)0.9048374180359595;  // float32(exp(-1/10))
    const int tid = threadIdx.x;
    const int lane = tid & 63;
    const int b = blockIdx.x;
    const int pix0 = b * PIXB;

    __shared__ unsigned lds_hist[HIST_W];
    __shared__ unsigned lds_arr[T_TOTAL];
    __shared__ unsigned lds_tot[T_TOTAL];

    for (int i = tid; i < HIST_W; i += STHR) lds_hist[i] = 0u;
    if (tid < T_TOTAL) { lds_arr[tid] = 0u; lds_tot[tid] = 0u; }
    __syncthreads();

    // fill LDS hist from this block's segment (coalesced u16 reads)
    {
        const int e0 = (int)seg_base[b];
        const int e1 = (int)seg_base[b + 1];
        for (int i = e0 + tid; i < e1; i += STHR) {
            unsigned lb = seg[i];
            atomicAdd(&lds_hist[lb >> 1], 1u << ((lb & 1u) << 4));
        }
    }
    __syncthreads();

    const bool has1 = tid < (NGROUP4 - STHR);   // second float4 group (450-256=194)
    float4 mem0 = make_float4(0.f, 0.f, 0.f, 0.f);
    float4 mem1 = make_float4(0.f, 0.f, 0.f, 0.f);
    float thr = 1.0f;

    for (int s = 0; s < T_TOTAL; ++s) {
        float* ob = out + (size_t)s * FRAME + pix0;
        int cnt = 0;

        {   // group g = tid
            float4 f;
            if (s < T_EVT) {
                int w = s * 900 + (tid << 1);
                unsigned w0 = lds_hist[w], w1 = lds_hist[w + 1];
                f = make_float4((float)(w0 & 0xFFFFu), (float)(w0 >> 16),
                                (float)(w1 & 0xFFFFu), (float)(w1 >> 16));
            } else f = make_float4(0.f, 0.f, 0.f, 0.f);
            float4 m, spk;
            m.x = mem0.x * decay; m.x = m.x + f.x;
            m.y = mem0.y * decay; m.y = m.y + f.y;
            m.z = mem0.z * decay; m.z = m.z + f.z;
            m.w = mem0.w * decay; m.w = m.w + f.w;
            spk.x = (m.x >= thr) ? 1.0f : 0.0f;
            spk.y = (m.y >= thr) ? 1.0f : 0.0f;
            spk.z = (m.z >= thr) ? 1.0f : 0.0f;
            spk.w = (m.w >= thr) ? 1.0f : 0.0f;
            ((float4*)ob)[tid] = spk;
            mem0.x = m.x - spk.x * thr;
            mem0.y = m.y - spk.y * thr;
            mem0.z = m.z - spk.z * thr;
            mem0.w = m.w - spk.w * thr;
            cnt += (int)spk.x + (int)spk.y + (int)spk.z + (int)spk.w;
        }
        if (has1) {   // group g = tid + 256
            int g = tid + STHR;
            float4 f;
            if (s < T_EVT) {
                int w = s * 900 + (g << 1);
                unsigned w0 = lds_hist[w], w1 = lds_hist[w + 1];
                f = make_float4((float)(w0 & 0xFFFFu), (float)(w0 >> 16),
                                (float)(w1 & 0xFFFFu), (float)(w1 >> 16));
            } else f = make_float4(0.f, 0.f, 0.f, 0.f);
            float4 m, spk;
            m.x = mem1.x * decay; m.x = m.x + f.x;
            m.y = mem1.y * decay; m.y = m.y + f.y;
            m.z = mem1.z * decay; m.z = m.z + f.z;
            m.w = mem1.w * decay; m.w = m.w + f.w;
            spk.x = (m.x >= thr) ? 1.0f : 0.0f;
            spk.y = (m.y >= thr) ? 1.0f : 0.0f;
            spk.z = (m.z >= thr) ? 1.0f : 0.0f;
            spk.w = (m.w >= thr) ? 1.0f : 0.0f;
            ((float4*)ob)[g] = spk;
            mem1.x = m.x - spk.x * thr;
            mem1.y = m.y - spk.y * thr;
            mem1.z = m.z - spk.z * thr;
            mem1.w = m.w - spk.w * thr;
            cnt += (int)spk.x + (int)spk.y + (int)spk.z + (int)spk.w;
        }

        if (s == T_TOTAL - 1) break;   // last step's count never consumed

        for (int off = 32; off > 0; off >>= 1) cnt += __shfl_down(cnt, off, 64);
        unsigned total;
        if (lane == 0) {
            unsigned old = __hip_atomic_fetch_add(&lds_arr[s],
                               (unsigned)cnt + (1u << 16),
                               __ATOMIC_RELAXED, __HIP_MEMORY_SCOPE_WORKGROUP);
            if ((old >> 16) == SWPB - 1) {
                unsigned bc = (old + (unsigned)cnt) & 0xFFFFu;
                const int g1 = b >> 4;           // 0..63
                unsigned long long a1 = __hip_atomic_fetch_add(
                    &g_n1[s][g1][0], (unsigned long long)bc + ARRIVE64,
                    __ATOMIC_RELAXED, __HIP_MEMORY_SCOPE_AGENT);
                if ((unsigned)(a1 >> 32) == 15u) {
                    unsigned c1 = (unsigned)a1 + bc;
                    const int g2 = g1 >> 4;      // 0..3
                    unsigned long long a2 = __hip_atomic_fetch_add(
                        &g_n2[s][g2][0], (unsigned long long)c1 + ARRIVE64,
                        __ATOMIC_RELAXED, __HIP_MEMORY_SCOPE_AGENT);
                    if ((unsigned)(a2 >> 32) == 15u) {
                        unsigned c2 = (unsigned)a2 + c1;
                        unsigned long long a3 = __hip_atomic_fetch_add(
                            &g_n3[s][0], (unsigned long long)c2 + ARRIVE64,
                            __ATOMIC_RELAXED, __HIP_MEMORY_SCOPE_AGENT);
                        if ((unsigned)(a3 >> 32) == 3u) {
                            unsigned tot = (unsigned)a3 + c2;
                            for (int g = 0; g < 64; ++g)
                                __hip_atomic_store(&g_relg[s][g][0], tot + 1u,
                                    __ATOMIC_RELAXED, __HIP_MEMORY_SCOPE_AGENT);
                        }
                    }
                }
                unsigned f;
                do {
                    __builtin_amdgcn_s_sleep(1);
                    f = __hip_atomic_load(&g_relg[s][g1][0], __ATOMIC_RELAXED,
                                          __HIP_MEMORY_SCOPE_AGENT);
                } while (f == 0u);
                total = f - 1u;
                __hip_atomic_store(&lds_tot[s], f,
                                   __ATOMIC_RELAXED, __HIP_MEMORY_SCOPE_WORKGROUP);
            } else {
                unsigned f;
                do {
                    __builtin_amdgcn_s_sleep(1);
                    f = __hip_atomic_load(&lds_tot[s], __ATOMIC_RELAXED,
                                          __HIP_MEMORY_SCOPE_WORKGROUP);
                } while (f == 0u);
                total = f - 1u;
            }
        }
        total = (unsigned)__shfl((int)total, 0, 64);
        float rate = (float)total / 1843200.0f;
        thr = thr + 0.1f * (rate - 0.1f);
        thr = fminf(fmaxf(thr, 0.1f), 10.0f);
    }
}

// ======================= old (fallback) path =======================
__global__ void scatter_kernel(const int* __restrict__ x, const int* __restrict__ y,
                               const int* __restrict__ p, const float* __restrict__ t,
                               unsigned* __restrict__ hist32, int n) {
    int i = blockIdx.x * blockDim.x + threadIdx.x;
    if (i >= n) return;
    float tmin = key2f(g_minkey);
    float tmax = key2f(g_maxkey);
    int ti = event_bin_t(t[i], tmin, tmax);
    int pix = event_pixel(x[i], y[i], p[i]);
    size_t bidx = (size_t)ti * FRAME + pix;
    atomicAdd(hist32 + (bidx >> 1), 1u << ((bidx & 1) << 4));
}

__global__ __launch_bounds__(ONTHR) void scan_old(float* __restrict__ out) {
#pragma clang fp contract(off)
    const float decay = (float)0.9048374180359595;
    const int gtid = blockIdx.x * ONTHR + threadIdx.x;
    const int lane = threadIdx.x & 63;
    const uint2 uz2 = make_uint2(0u, 0u);
    float4 mem0 = make_float4(0.f, 0.f, 0.f, 0.f);
    float4 mem1 = make_float4(0.f, 0.f, 0.f, 0.f);
    const bool has1 = (gtid + ONT) < FRAME4;
    float thr = 1.0f;
    const uint2* hist2 = (const uint2*)(out + (size_t)T_EVT * FRAME);
    __shared__ unsigned lds_arr[T_TOTAL];
    __shared__ unsigned lds_tot[T_TOTAL];
    if (threadIdx.x < T_TOTAL) { lds_arr[threadIdx.x] = 0u; lds_tot[threadIdx.x] = 0u; }
    __syncthreads();
    uint2 u0 = hist2[gtid];
    uint2 u1 = has1 ? hist2[gtid + ONT] : uz2;
    for (int s = 0; s < T_TOTAL; ++s) {
        float4* o4 = (float4*)(out + (size_t)s * FRAME);
        int cnt = 0;
        {
            float4 m, spk;
            m.x = mem0.x * decay; m.x = m.x + (float)(u0.x & 0xFFFFu);
            m.y = mem0.y * decay; m.y = m.y + (float)(u0.x >> 16);
            m.z = mem0.z * decay; m.z = m.z + (float)(u0.y & 0xFFFFu);
            m.w = mem0.w * decay; m.w = m.w + (float)(u0.y >> 16);
            spk.x = (m.x >= thr) ? 1.0f : 0.0f;
            spk.y = (m.y >= thr) ? 1.0f : 0.0f;
            spk.z = (m.z >= thr) ? 1.0f : 0.0f;
            spk.w = (m.w >= thr) ? 1.0f : 0.0f;
            o4[gtid] = spk;
            mem0.x = m.x - spk.x * thr; mem0.y = m.y - spk.y * thr;
            mem0.z = m.z - spk.z * thr; mem0.w = m.w - spk.w * thr;
            cnt += (int)spk.x + (int)spk.y + (int)spk.z + (int)spk.w;
        }
        if (has1) {
            float4 m, spk;
            m.x = mem1.x * decay; m.x = m.x + (float)(u1.x & 0xFFFFu);
            m.y = mem1.y * decay; m.y = m.y + (float)(u1.x >> 16);
            m.z = mem1.z * decay; m.z = m.z + (float)(u1.y & 0xFFFFu);
            m.w = mem1.w * decay; m.w = m.w + (float)(u1.y >> 16);
            spk.x = (m.x >= thr) ? 1.0f : 0.0f;
            spk.y = (m.y >= thr) ? 1.0f : 0.0f;
            spk.z = (m.z >= thr) ? 1.0f : 0.0f;
            spk.w = (m.w >= thr) ? 1.0f : 0.0f;
            o4[gtid + ONT] = spk;
            mem1.x = m.x - spk.x * thr; mem1.y = m.y - spk.y * thr;
            mem1.z = m.z - spk.z * thr; mem1.w = m.w - spk.w * thr;
            cnt += (int)spk.x + (int)spk.y + (int)spk.z + (int)spk.w;
        }
        if (s + 1 < T_EVT) {
            const uint2* hn = hist2 + (size_t)(s + 1) * FRAME4;
            u0 = hn[gtid];
            u1 = has1 ? hn[gtid + ONT] : uz2;
        } else { u0 = uz2; u1 = uz2; }
        if (s == T_TOTAL - 1) break;
        for (int off = 32; off > 0; off >>= 1) cnt += __shfl_down(cnt, off, 64);
        unsigned total;
        if (lane == 0) {
            unsigned old = __hip_atomic_fetch_add(&lds_arr[s],
                               (unsigned)cnt + (1u << 16),
                               __ATOMIC_RELAXED, __HIP_MEMORY_SCOPE_WORKGROUP);
            if ((old >> 16) == ONWPB - 1) {
                unsigned bc = (old + (unsigned)cnt) & 0xFFFFu;
                const int gid = blockIdx.x >> 4;
                unsigned long long gold = __hip_atomic_fetch_add(
                    &g_grp[s][gid][0], (unsigned long long)bc + ARRIVE64,
                    __ATOMIC_RELAXED, __HIP_MEMORY_SCOPE_AGENT);
                if ((unsigned)(gold >> 32) == 15u) {
                    unsigned gc = (unsigned)gold + bc;
                    unsigned long long told = __hip_atomic_fetch_add(
                        &g_top[s][0], (unsigned long long)gc + ARRIVE64,
                        __ATOMIC_RELAXED, __HIP_MEMORY_SCOPE_AGENT);
                    if ((unsigned)(told >> 32) == 15u) {
                        unsigned tot = (unsigned)told + gc;
                        __hip_atomic_store(&g_rel[s][0], tot + 1u,
                                           __ATOMIC_RELAXED, __HIP_MEMORY_SCOPE_AGENT);
                    }
                }
                unsigned f;
                do {
                    __builtin_amdgcn_s_sleep(1);
                    f = __hip_atomic_load(&g_rel[s][0], __ATOMIC_RELAXED,
                                          __HIP_MEMORY_SCOPE_AGENT);
                } while (f == 0u);
                total = f - 1u;
                __hip_atomic_store(&lds_tot[s], f,
                                   __ATOMIC_RELAXED, __HIP_MEMORY_SCOPE_WORKGROUP);
            } else {
                unsigned f;
                do {
                    __builtin_amdgcn_s_sleep(1);
                    f = __hip_atomic_load(&lds_tot[s], __ATOMIC_RELAXED,
                                          __HIP_MEMORY_SCOPE_WORKGROUP);
                } while (f == 0u);
                total = f - 1u;
            }
        }
        total = (unsigned)__shfl((int)total, 0, 64);
        float rate = (float)total / 1843200.0f;
        thr = thr + 0.1f * (rate - 0.1f);
        thr = fminf(fmaxf(thr, 0.1f), 10.0f);
    }
}

extern "C" void kernel_launch(void* const* d_in, const int* in_sizes, int n_in,
                              void* d_out, int out_size, void* d_ws, size_t ws_size,
                              hipStream_t stream) {
    const int*   x = (const int*)d_in[0];
    const int*   y = (const int*)d_in[1];
    const int*   p = (const int*)d_in[2];
    const float* t = (const float*)d_in[3];
    float* out = (float*)d_out;
    const int n = in_sizes[0];

    init_kernel<<<64, 256, 0, stream>>>();

    if (d_ws != nullptr && ws_size >= WS_NEED(n)) {
        unsigned* mat = (unsigned*)((char*)d_ws + MAT_OFF);
        unsigned* seg_base = (unsigned*)((char*)d_ws + SB_OFF);
        unsigned short* seg = (unsigned short*)((char*)d_ws + SEG_OFF);

        minmax_kernel<<<1024, 256, 0, stream>>>(t, n);
        passA_kernel<<<RBLK, 256, 0, stream>>>(x, y, p, t, mat, n);
        offsets_kernel<<<1, NBUCKET, 0, stream>>>(mat, seg_base, n);
        passB_kernel<<<RBLK, 256, 0, stream>>>(x, y, p, t, mat, seg_base, seg, n);

        dim3 g(SBLK), b(STHR);
        void* args[] = { (void*)&out, (void*)&seg, (void*)&seg_base };
        hipLaunchCooperativeKernel((void*)scan_new, g, b, args, 0, stream);
    } else {
        unsigned* hist32 = (unsigned*)(out + (size_t)T_EVT * FRAME);
        minmax_zero_kernel<<<1024, 256, 0, stream>>>(t, n, (uint4*)hist32);
        scatter_kernel<<<(n + 255) / 256, 256, 0, stream>>>(x, y, p, t, hist32, n);
        dim3 g(ONBLK), b(ONTHR);
        void* args[] = { (void*)&out };
        hipLaunchCooperativeKernel((void*)scan_old, g, b, args, 0, stream);
    }
}

// Round 10
// 395.051 us; speedup vs baseline: 7.6028x; 1.0506x over previous
//
#include <hip/hip_runtime.h>
#include <cstddef>

#define HH 720
#define WW 1280
#define FRAME 1843200            // 2*720*1280
#define FRAME4 460800            // FRAME/4
#define T_EVT 10
#define T_TOTAL 20
#define ARRIVE64 (1ULL << 32)

// ---------- old (fallback) path config ----------
#define ONBLK 256
#define ONTHR 1024
#define ONWPB 16
#define ONT (ONBLK * ONTHR)

// ---------- new path config ----------
#define SBLK 1024                // scan blocks (4 per CU)
#define STHR 256                 // scan threads per block (4 waves)
#define SWPB 4
#define PIXB 1800                // pixels per scan block
#define NGROUP4 450              // float4 groups per block (1800/4)
#define HIST_W 9000              // LDS hist words (18000 u16)
#define RBLK 256                 // passA/passB blocks
#define NBUCKET 1024

// ws layout (bytes), all 256-aligned
#define MAT_OFF   0u                           // u32[256*1024] = 1 MB
#define CS_OFF    (256u * 1024u * 4u)          // u32[1024] column sums
#define SB_OFF    (CS_OFF + 4096u)             // u32[1025] seg bases
#define KEY_OFF   (SB_OFF + 8192u)             // u32[n] packed keys
#define SEG_OFF(n) (KEY_OFF + 4u * (unsigned)(n))        // u16[n]
#define WS_NEED(n) ((size_t)SEG_OFF(n) + 2ull * (size_t)(n) + 256ull)

// Persistent device globals.
__device__ unsigned g_minkey;
__device__ unsigned g_maxkey;
// old-path tree (R8, proven)
__device__ unsigned long long g_grp[T_TOTAL][16][16];
__device__ unsigned long long g_top[T_TOTAL][16];
__device__ unsigned g_rel[T_TOTAL][32];
// new-path tree: 1024 -> 64 -> 4 -> 1, fan-out to 64 group-release words
__device__ unsigned long long g_n1[T_TOTAL][64][16];
__device__ unsigned long long g_n2[T_TOTAL][4][16];
__device__ unsigned long long g_n3[T_TOTAL][16];
__device__ unsigned g_relg[T_TOTAL][64][32];   // [s][group][0]: total+1

__device__ __forceinline__ unsigned f2key(float f) {
    unsigned b = __float_as_uint(f);
    return b ^ ((unsigned)(((int)b) >> 31) | 0x80000000u);
}
__device__ __forceinline__ float key2f(unsigned k) {
    unsigned b = (k & 0x80000000u) ? (k ^ 0x80000000u) : ~k;
    return __uint_as_float(b);
}

// Exact reference bin: ((t-tmin)/(tmax-tmin))*(10-1e-6), trunc, clip.
__device__ __forceinline__ int event_bin_t(float tv, float tmin, float tmax) {
#pragma clang fp contract(off)
    float tn;
    if (tmax > tmin) tn = (tv - tmin) / (tmax - tmin) * (float)(10.0 - 1e-6);
    else tn = 0.0f;
    int ti = (int)tn;
    return ti < 0 ? 0 : (ti > T_EVT - 1 ? T_EVT - 1 : ti);
}
__device__ __forceinline__ int event_pixel(int xi, int yi, int ci) {
    xi = xi < 0 ? 0 : (xi > WW - 1 ? WW - 1 : xi);
    yi = yi < 0 ? 0 : (yi > HH - 1 ? HH - 1 : yi);
    return ci * (HH * WW) + yi * WW + xi;
}

__global__ void init_kernel() {
    const int gtid = blockIdx.x * blockDim.x + threadIdx.x;
    const int gs = gridDim.x * blockDim.x;
    if (gtid == 0) { g_minkey = 0xFFFFFFFFu; g_maxkey = 0u; }
    unsigned long long* a = &g_grp[0][0][0];
    for (int i = gtid; i < T_TOTAL * 16 * 16; i += gs) a[i] = 0ull;
    unsigned long long* b = &g_top[0][0];
    for (int i = gtid; i < T_TOTAL * 16; i += gs) b[i] = 0ull;
    unsigned* c = &g_rel[0][0];
    for (int i = gtid; i < T_TOTAL * 32; i += gs) c[i] = 0u;
    unsigned long long* d = &g_n1[0][0][0];
    for (int i = gtid; i < T_TOTAL * 64 * 16; i += gs) d[i] = 0ull;
    unsigned long long* e = &g_n2[0][0][0];
    for (int i = gtid; i < T_TOTAL * 4 * 16; i += gs) e[i] = 0ull;
    unsigned long long* f = &g_n3[0][0];
    for (int i = gtid; i < T_TOTAL * 16; i += gs) f[i] = 0ull;
    unsigned* g = &g_relg[0][0][0];
    for (int i = gtid; i < T_TOTAL * 64 * 32; i += gs) g[i] = 0u;
}

// ======================= shared: t min/max =======================
__device__ __forceinline__ void minmax_body(const float* __restrict__ t, int n,
                                            int gtid, int gstride) {
    unsigned mn = 0xFFFFFFFFu, mx = 0u;
    const int n4 = n >> 2;
    const float4* t4 = (const float4*)t;
    for (int i = gtid; i < n4; i += gstride) {
        float4 tv = t4[i];
        unsigned k0 = f2key(tv.x), k1 = f2key(tv.y);
        unsigned k2 = f2key(tv.z), k3 = f2key(tv.w);
        unsigned a = k0 < k1 ? k0 : k1, b = k2 < k3 ? k2 : k3;
        unsigned c = a < b ? a : b;
        mn = mn < c ? mn : c;
        a = k0 > k1 ? k0 : k1; b = k2 > k3 ? k2 : k3;
        c = a > b ? a : b;
        mx = mx > c ? mx : c;
    }
    for (int i = (n4 << 2) + gtid; i < n; i += gstride) {
        unsigned k = f2key(t[i]);
        mn = mn < k ? mn : k;
        mx = mx > k ? mx : k;
    }
    for (int off = 32; off > 0; off >>= 1) {
        unsigned omn = (unsigned)__shfl_down((int)mn, off, 64);
        unsigned omx = (unsigned)__shfl_down((int)mx, off, 64);
        mn = mn < omn ? mn : omn;
        mx = mx > omx ? mx : omx;
    }
    __shared__ unsigned smn[16], smx[16];
    int lane = threadIdx.x & 63, wv = threadIdx.x >> 6;
    if (lane == 0) { smn[wv] = mn; smx[wv] = mx; }
    __syncthreads();
    if (threadIdx.x == 0) {
        int nw = blockDim.x >> 6;
        for (int i = 1; i < nw; ++i) {
            mn = mn < smn[i] ? mn : smn[i];
            mx = mx > smx[i] ? mx : smx[i];
        }
        atomicMin(&g_minkey, mn);
        atomicMax(&g_maxkey, mx);
    }
}

__global__ void minmax_kernel(const float* __restrict__ t, int n) {
    minmax_body(t, n, blockIdx.x * blockDim.x + threadIdx.x,
                gridDim.x * blockDim.x);
}

__global__ void minmax_zero_kernel(const float* __restrict__ t, int n,
                                   uint4* __restrict__ hist16v) {
    const int gtid = blockIdx.x * blockDim.x + threadIdx.x;
    const int gstride = gridDim.x * blockDim.x;
    const uint4 z = make_uint4(0u, 0u, 0u, 0u);
    const int nz = T_EVT * FRAME / 8;
    for (int i = gtid; i < nz; i += gstride) hist16v[i] = z;
    minmax_body(t, n, gtid, gstride);
}

// ======================= new path: counting sort =======================
// passA: decode events ONCE -> packed key (ti<<21 | pix) + LDS bucket counts.
__global__ void passA_kernel(const int* __restrict__ x, const int* __restrict__ y,
                             const int* __restrict__ p, const float* __restrict__ t,
                             unsigned* __restrict__ mat, unsigned* __restrict__ keys,
                             int n) {
    __shared__ unsigned cnt[NBUCKET];
    for (int i = threadIdx.x; i < NBUCKET; i += blockDim.x) cnt[i] = 0u;
    __syncthreads();
    const float tmin = key2f(g_minkey);
    const float tmax = key2f(g_maxkey);
    const int chunk = (n + (int)gridDim.x - 1) / (int)gridDim.x;
    const int s0 = blockIdx.x * chunk;
    const int s1 = min(n, s0 + chunk);
    for (int i = s0 + threadIdx.x; i < s1; i += blockDim.x) {
        int pix = event_pixel(x[i], y[i], p[i]);
        int ti = event_bin_t(t[i], tmin, tmax);
        keys[i] = ((unsigned)ti << 21) | (unsigned)pix;   // pix < 2^21
        atomicAdd(&cnt[pix / PIXB], 1u);
    }
    __syncthreads();
    for (int i = threadIdx.x; i < NBUCKET; i += blockDim.x)
        mat[blockIdx.x * NBUCKET + i] = cnt[i];
}

// one block PER BUCKET COLUMN: exclusive scan of the 256 row counts.
__global__ void offsets_col_kernel(unsigned* __restrict__ mat,
                                   unsigned* __restrict__ colsum) {
    const int j = blockIdx.x;        // bucket
    const int r = threadIdx.x;       // row (passA block)
    const int lane = r & 63, wv = r >> 6;
    unsigned v = mat[r * NBUCKET + j];
    unsigned incl = v;
    for (int off = 1; off < 64; off <<= 1) {
        unsigned o = (unsigned)__shfl_up((int)incl, off, 64);
        if (lane >= off) incl += o;
    }
    __shared__ unsigned wtot[4];
    if (lane == 63) wtot[wv] = incl;
    __syncthreads();
    if (r == 0) {
        unsigned run = 0;
#pragma unroll
        for (int k = 0; k < 4; ++k) { unsigned tmp = wtot[k]; wtot[k] = run; run += tmp; }
    }
    __syncthreads();
    unsigned ex = incl - v + wtot[wv];
    mat[r * NBUCKET + j] = ex;
    if (r == 255) colsum[j] = ex + v;
}

// one block, 1024 threads: exclusive scan of bucket totals -> seg bases.
__global__ void offsets_top_kernel(const unsigned* __restrict__ colsum,
                                   unsigned* __restrict__ seg_base) {
    const int j = threadIdx.x;
    const int lane = j & 63, wv = j >> 6;
    unsigned v = colsum[j];
    unsigned incl = v;
    for (int off = 1; off < 64; off <<= 1) {
        unsigned o = (unsigned)__shfl_up((int)incl, off, 64);
        if (lane >= off) incl += o;
    }
    __shared__ unsigned wtot[16];
    if (lane == 63) wtot[wv] = incl;
    __syncthreads();
    if (j == 0) {
        unsigned run = 0;
#pragma unroll
        for (int k = 0; k < 16; ++k) { unsigned tmp = wtot[k]; wtot[k] = run; run += tmp; }
    }
    __syncthreads();
    unsigned ex = incl - v + wtot[wv];
    seg_base[j] = ex;
    if (j == NBUCKET - 1) seg_base[NBUCKET] = ex + v;
}

// passB: read packed keys only; LDS-rank; scatter u16 local bin.
__global__ void passB_kernel(const unsigned* __restrict__ keys,
                             const unsigned* __restrict__ mat,
                             const unsigned* __restrict__ seg_base,
                             unsigned short* __restrict__ seg, int n) {
    __shared__ unsigned base[NBUCKET];
    for (int i = threadIdx.x; i < NBUCKET; i += blockDim.x)
        base[i] = mat[blockIdx.x * NBUCKET + i] + seg_base[i];
    __syncthreads();
    const int chunk = (n + (int)gridDim.x - 1) / (int)gridDim.x;
    const int s0 = blockIdx.x * chunk;
    const int s1 = min(n, s0 + chunk);
    for (int i = s0 + threadIdx.x; i < s1; i += blockDim.x) {
        unsigned k = keys[i];
        int pix = (int)(k & 0x1FFFFFu);
        int ti = (int)(k >> 21);
        int bkt = pix / PIXB;
        int lb = ti * PIXB + (pix - bkt * PIXB);   // < 18000
        unsigned idx = atomicAdd(&base[bkt], 1u);
        seg[idx] = (unsigned short)lb;
    }
}

// Cooperative scan, 1024 blocks x 256 thr, 36 KB LDS hist (R9, proven).
__global__ __launch_bounds__(STHR, 4) void scan_new(float* __restrict__ out,
                                                    const unsigned short* __restrict__ seg,
                                                    const unsigned* __restrict__ seg_base) {
#pragma clang fp contract(off)
    const float decay = (float)0.9048374180359595;  // float32(exp(-1/10))
    const int tid = threadIdx.x;
    const int lane = tid & 63;
    const int b = blockIdx.x;
    const int pix0 = b * PIXB;

    __shared__ unsigned lds_hist[HIST_W];
    __shared__ unsigned lds_arr[T_TOTAL];
    __shared__ unsigned lds_tot[T_TOTAL];

    for (int i = tid; i < HIST_W; i += STHR) lds_hist[i] = 0u;
    if (tid < T_TOTAL) { lds_arr[tid] = 0u; lds_tot[tid] = 0u; }
    __syncthreads();

    {
        const int e0 = (int)seg_base[b];
        const int e1 = (int)seg_base[b + 1];
        for (int i = e0 + tid; i < e1; i += STHR) {
            unsigned lb = seg[i];
            atomicAdd(&lds_hist[lb >> 1], 1u << ((lb & 1u) << 4));
        }
    }
    __syncthreads();

    const bool has1 = tid < (NGROUP4 - STHR);
    float4 mem0 = make_float4(0.f, 0.f, 0.f, 0.f);
    float4 mem1 = make_float4(0.f, 0.f, 0.f, 0.f);
    float thr = 1.0f;

    for (int s = 0; s < T_TOTAL; ++s) {
        float* ob = out + (size_t)s * FRAME + pix0;
        int cnt = 0;

        {
            float4 f;
            if (s < T_EVT) {
                int w = s * 900 + (tid << 1);
                unsigned w0 = lds_hist[w], w1 = lds_hist[w + 1];
                f = make_float4((float)(w0 & 0xFFFFu), (float)(w0 >> 16),
                                (float)(w1 & 0xFFFFu), (float)(w1 >> 16));
            } else f = make_float4(0.f, 0.f, 0.f, 0.f);
            float4 m, spk;
            m.x = mem0.x * decay; m.x = m.x + f.x;
            m.y = mem0.y * decay; m.y = m.y + f.y;
            m.z = mem0.z * decay; m.z = m.z + f.z;
            m.w = mem0.w * decay; m.w = m.w + f.w;
            spk.x = (m.x >= thr) ? 1.0f : 0.0f;
            spk.y = (m.y >= thr) ? 1.0f : 0.0f;
            spk.z = (m.z >= thr) ? 1.0f : 0.0f;
            spk.w = (m.w >= thr) ? 1.0f : 0.0f;
            ((float4*)ob)[tid] = spk;
            mem0.x = m.x - spk.x * thr;
            mem0.y = m.y - spk.y * thr;
            mem0.z = m.z - spk.z * thr;
            mem0.w = m.w - spk.w * thr;
            cnt += (int)spk.x + (int)spk.y + (int)spk.z + (int)spk.w;
        }
        if (has1) {
            int g = tid + STHR;
            float4 f;
            if (s < T_EVT) {
                int w = s * 900 + (g << 1);
                unsigned w0 = lds_hist[w], w1 = lds_hist[w + 1];
                f = make_float4((float)(w0 & 0xFFFFu), (float)(w0 >> 16),
                                (float)(w1 & 0xFFFFu), (float)(w1 >> 16));
            } else f = make_float4(0.f, 0.f, 0.f, 0.f);
            float4 m, spk;
            m.x = mem1.x * decay; m.x = m.x + f.x;
            m.y = mem1.y * decay; m.y = m.y + f.y;
            m.z = mem1.z * decay; m.z = m.z + f.z;
            m.w = mem1.w * decay; m.w = m.w + f.w;
            spk.x = (m.x >= thr) ? 1.0f : 0.0f;
            spk.y = (m.y >= thr) ? 1.0f : 0.0f;
            spk.z = (m.z >= thr) ? 1.0f : 0.0f;
            spk.w = (m.w >= thr) ? 1.0f : 0.0f;
            ((float4*)ob)[g] = spk;
            mem1.x = m.x - spk.x * thr;
            mem1.y = m.y - spk.y * thr;
            mem1.z = m.z - spk.z * thr;
            mem1.w = m.w - spk.w * thr;
            cnt += (int)spk.x + (int)spk.y + (int)spk.z + (int)spk.w;
        }

        if (s == T_TOTAL - 1) break;

        for (int off = 32; off > 0; off >>= 1) cnt += __shfl_down(cnt, off, 64);
        unsigned total;
        if (lane == 0) {
            unsigned old = __hip_atomic_fetch_add(&lds_arr[s],
                               (unsigned)cnt + (1u << 16),
                               __ATOMIC_RELAXED, __HIP_MEMORY_SCOPE_WORKGROUP);
            if ((old >> 16) == SWPB - 1) {
                unsigned bc = (old + (unsigned)cnt) & 0xFFFFu;
                const int g1 = b >> 4;
                unsigned long long a1 = __hip_atomic_fetch_add(
                    &g_n1[s][g1][0], (unsigned long long)bc + ARRIVE64,
                    __ATOMIC_RELAXED, __HIP_MEMORY_SCOPE_AGENT);
                if ((unsigned)(a1 >> 32) == 15u) {
                    unsigned c1 = (unsigned)a1 + bc;
                    const int g2 = g1 >> 4;
                    unsigned long long a2 = __hip_atomic_fetch_add(
                        &g_n2[s][g2][0], (unsigned long long)c1 + ARRIVE64,
                        __ATOMIC_RELAXED, __HIP_MEMORY_SCOPE_AGENT);
                    if ((unsigned)(a2 >> 32) == 15u) {
                        unsigned c2 = (unsigned)a2 + c1;
                        unsigned long long a3 = __hip_atomic_fetch_add(
                            &g_n3[s][0], (unsigned long long)c2 + ARRIVE64,
                            __ATOMIC_RELAXED, __HIP_MEMORY_SCOPE_AGENT);
                        if ((unsigned)(a3 >> 32) == 3u) {
                            unsigned tot = (unsigned)a3 + c2;
                            for (int g = 0; g < 64; ++g)
                                __hip_atomic_store(&g_relg[s][g][0], tot + 1u,
                                    __ATOMIC_RELAXED, __HIP_MEMORY_SCOPE_AGENT);
                        }
                    }
                }
                unsigned f;
                do {
                    __builtin_amdgcn_s_sleep(1);
                    f = __hip_atomic_load(&g_relg[s][g1][0], __ATOMIC_RELAXED,
                                          __HIP_MEMORY_SCOPE_AGENT);
                } while (f == 0u);
                total = f - 1u;
                __hip_atomic_store(&lds_tot[s], f,
                                   __ATOMIC_RELAXED, __HIP_MEMORY_SCOPE_WORKGROUP);
            } else {
                unsigned f;
                do {
                    __builtin_amdgcn_s_sleep(1);
                    f = __hip_atomic_load(&lds_tot[s], __ATOMIC_RELAXED,
                                          __HIP_MEMORY_SCOPE_WORKGROUP);
                } while (f == 0u);
                total = f - 1u;
            }
        }
        total = (unsigned)__shfl((int)total, 0, 64);
        float rate = (float)total / 1843200.0f;
        thr = thr + 0.1f * (rate - 0.1f);
        thr = fminf(fmaxf(thr, 0.1f), 10.0f);
    }
}

// ======================= old (fallback) path =======================
__global__ void scatter_kernel(const int* __restrict__ x, const int* __restrict__ y,
                               const int* __restrict__ p, const float* __restrict__ t,
                               unsigned* __restrict__ hist32, int n) {
    int i = blockIdx.x * blockDim.x + threadIdx.x;
    if (i >= n) return;
    float tmin = key2f(g_minkey);
    float tmax = key2f(g_maxkey);
    int ti = event_bin_t(t[i], tmin, tmax);
    int pix = event_pixel(x[i], y[i], p[i]);
    size_t bidx = (size_t)ti * FRAME + pix;
    atomicAdd(hist32 + (bidx >> 1), 1u << ((bidx & 1) << 4));
}

__global__ __launch_bounds__(ONTHR) void scan_old(float* __restrict__ out) {
#pragma clang fp contract(off)
    const float decay = (float)0.9048374180359595;
    const int gtid = blockIdx.x * ONTHR + threadIdx.x;
    const int lane = threadIdx.x & 63;
    const uint2 uz2 = make_uint2(0u, 0u);
    float4 mem0 = make_float4(0.f, 0.f, 0.f, 0.f);
    float4 mem1 = make_float4(0.f, 0.f, 0.f, 0.f);
    const bool has1 = (gtid + ONT) < FRAME4;
    float thr = 1.0f;
    const uint2* hist2 = (const uint2*)(out + (size_t)T_EVT * FRAME);
    __shared__ unsigned lds_arr[T_TOTAL];
    __shared__ unsigned lds_tot[T_TOTAL];
    if (threadIdx.x < T_TOTAL) { lds_arr[threadIdx.x] = 0u; lds_tot[threadIdx.x] = 0u; }
    __syncthreads();
    uint2 u0 = hist2[gtid];
    uint2 u1 = has1 ? hist2[gtid + ONT] : uz2;
    for (int s = 0; s < T_TOTAL; ++s) {
        float4* o4 = (float4*)(out + (size_t)s * FRAME);
        int cnt = 0;
        {
            float4 m, spk;
            m.x = mem0.x * decay; m.x = m.x + (float)(u0.x & 0xFFFFu);
            m.y = mem0.y * decay; m.y = m.y + (float)(u0.x >> 16);
            m.z = mem0.z * decay; m.z = m.z + (float)(u0.y & 0xFFFFu);
            m.w = mem0.w * decay; m.w = m.w + (float)(u0.y >> 16);
            spk.x = (m.x >= thr) ? 1.0f : 0.0f;
            spk.y = (m.y >= thr) ? 1.0f : 0.0f;
            spk.z = (m.z >= thr) ? 1.0f : 0.0f;
            spk.w = (m.w >= thr) ? 1.0f : 0.0f;
            o4[gtid] = spk;
            mem0.x = m.x - spk.x * thr; mem0.y = m.y - spk.y * thr;
            mem0.z = m.z - spk.z * thr; mem0.w = m.w - spk.w * thr;
            cnt += (int)spk.x + (int)spk.y + (int)spk.z + (int)spk.w;
        }
        if (has1) {
            float4 m, spk;
            m.x = mem1.x * decay; m.x = m.x + (float)(u1.x & 0xFFFFu);
            m.y = mem1.y * decay; m.y = m.y + (float)(u1.x >> 16);
            m.z = mem1.z * decay; m.z = m.z + (float)(u1.y & 0xFFFFu);
            m.w = mem1.w * decay; m.w = m.w + (float)(u1.y >> 16);
            spk.x = (m.x >= thr) ? 1.0f : 0.0f;
            spk.y = (m.y >= thr) ? 1.0f : 0.0f;
            spk.z = (m.z >= thr) ? 1.0f : 0.0f;
            spk.w = (m.w >= thr) ? 1.0f : 0.0f;
            o4[gtid + ONT] = spk;
            mem1.x = m.x - spk.x * thr; mem1.y = m.y - spk.y * thr;
            mem1.z = m.z - spk.z * thr; mem1.w = m.w - spk.w * thr;
            cnt += (int)spk.x + (int)spk.y + (int)spk.z + (int)spk.w;
        }
        if (s + 1 < T_EVT) {
            const uint2* hn = hist2 + (size_t)(s + 1) * FRAME4;
            u0 = hn[gtid];
            u1 = has1 ? hn[gtid + ONT] : uz2;
        } else { u0 = uz2; u1 = uz2; }
        if (s == T_TOTAL - 1) break;
        for (int off = 32; off > 0; off >>= 1) cnt += __shfl_down(cnt, off, 64);
        unsigned total;
        if (lane == 0) {
            unsigned old = __hip_atomic_fetch_add(&lds_arr[s],
                               (unsigned)cnt + (1u << 16),
                               __ATOMIC_RELAXED, __HIP_MEMORY_SCOPE_WORKGROUP);
            if ((old >> 16) == ONWPB - 1) {
                unsigned bc = (old + (unsigned)cnt) & 0xFFFFu;
                const int gid = blockIdx.x >> 4;
                unsigned long long gold = __hip_atomic_fetch_add(
                    &g_grp[s][gid][0], (unsigned long long)bc + ARRIVE64,
                    __ATOMIC_RELAXED, __HIP_MEMORY_SCOPE_AGENT);
                if ((unsigned)(gold >> 32) == 15u) {
                    unsigned gc = (unsigned)gold + bc;
                    unsigned long long told = __hip_atomic_fetch_add(
                        &g_top[s][0], (unsigned long long)gc + ARRIVE64,
                        __ATOMIC_RELAXED, __HIP_MEMORY_SCOPE_AGENT);
                    if ((unsigned)(told >> 32) == 15u) {
                        unsigned tot = (unsigned)told + gc;
                        __hip_atomic_store(&g_rel[s][0], tot + 1u,
                                           __ATOMIC_RELAXED, __HIP_MEMORY_SCOPE_AGENT);
                    }
                }
                unsigned f;
                do {
                    __builtin_amdgcn_s_sleep(1);
                    f = __hip_atomic_load(&g_rel[s][0], __ATOMIC_RELAXED,
                                          __HIP_MEMORY_SCOPE_AGENT);
                } while (f == 0u);
                total = f - 1u;
                __hip_atomic_store(&lds_tot[s], f,
                                   __ATOMIC_RELAXED, __HIP_MEMORY_SCOPE_WORKGROUP);
            } else {
                unsigned f;
                do {
                    __builtin_amdgcn_s_sleep(1);
                    f = __hip_atomic_load(&lds_tot[s], __ATOMIC_RELAXED,
                                          __HIP_MEMORY_SCOPE_WORKGROUP);
                } while (f == 0u);
                total = f - 1u;
            }
        }
        total = (unsigned)__shfl((int)total, 0, 64);
        float rate = (float)total / 1843200.0f;
        thr = thr + 0.1f * (rate - 0.1f);
        thr = fminf(fmaxf(thr, 0.1f), 10.0f);
    }
}

extern "C" void kernel_launch(void* const* d_in, const int* in_sizes, int n_in,
                              void* d_out, int out_size, void* d_ws, size_t ws_size,
                              hipStream_t stream) {
    const int*   x = (const int*)d_in[0];
    const int*   y = (const int*)d_in[1];
    const int*   p = (const int*)d_in[2];
    const float* t = (const float*)d_in[3];
    float* out = (float*)d_out;
    const int n = in_sizes[0];

    init_kernel<<<64, 256, 0, stream>>>();

    if (d_ws != nullptr && ws_size >= WS_NEED(n)) {
        unsigned* mat = (unsigned*)((char*)d_ws + MAT_OFF);
        unsigned* colsum = (unsigned*)((char*)d_ws + CS_OFF);
        unsigned* seg_base = (unsigned*)((char*)d_ws + SB_OFF);
        unsigned* keys = (unsigned*)((char*)d_ws + KEY_OFF);
        unsigned short* seg = (unsigned short*)((char*)d_ws + SEG_OFF(n));

        minmax_kernel<<<1024, 256, 0, stream>>>(t, n);
        passA_kernel<<<RBLK, 256, 0, stream>>>(x, y, p, t, mat, keys, n);
        offsets_col_kernel<<<NBUCKET, 256, 0, stream>>>(mat, colsum);
        offsets_top_kernel<<<1, NBUCKET, 0, stream>>>(colsum, seg_base);
        passB_kernel<<<RBLK, 256, 0, stream>>>(keys, mat, seg_base, seg, n);

        dim3 g(SBLK), b(STHR);
        void* args[] = { (void*)&out, (void*)&seg, (void*)&seg_base };
        hipLaunchCooperativeKernel((void*)scan_new, g, b, args, 0, stream);
    } else {
        unsigned* hist32 = (unsigned*)(out + (size_t)T_EVT * FRAME);
        minmax_zero_kernel<<<1024, 256, 0, stream>>>(t, n, (uint4*)hist32);
        scatter_kernel<<<(n + 255) / 256, 256, 0, stream>>>(x, y, p, t, hist32, n);
        dim3 g(ONBLK), b(ONTHR);
        void* args[] = { (void*)&out };
        hipLaunchCooperativeKernel((void*)scan_old, g, b, args, 0, stream);
    }
}

// Round 11
// 366.539 us; speedup vs baseline: 8.1942x; 1.0778x over previous
//
#include <hip/hip_runtime.h>
#include <cstddef>

#define HH 720
#define WW 1280
#define FRAME 1843200            // 2*720*1280
#define FRAME4 460800            // FRAME/4
#define T_EVT 10
#define T_TOTAL 20
#define ARRIVE64 (1ULL << 32)

// ---------- old (fallback) path config ----------
#define ONBLK 256
#define ONTHR 1024
#define ONWPB 16
#define ONT (ONBLK * ONTHR)

// ---------- new path config ----------
#define SBLK 1024                // scan blocks (4 per CU)
#define STHR 256                 // scan threads per block (4 waves)
#define SWPB 4
#define PIXB 1800                // pixels per scan block
#define NGROUP4 450              // float4 groups per block (1800/4)
#define HIST_W 9000              // LDS hist words (18000 u16)
#define RBLK 512                 // passA/passB blocks (x1024 thr = 32 waves/CU)
#define RTHR 1024
#define NBUCKET 1024

// ws layout (bytes), all 256-aligned
#define MAT_OFF   0u                           // u32[512*1024] = 2 MB
#define CS_OFF    (512u * 1024u * 4u)          // u32[1024] column sums
#define SB_OFF    (CS_OFF + 4096u)             // u32[1025] seg bases
#define KEY_OFF   (SB_OFF + 8192u)             // u32[n] packed keys
#define SEG_OFF(n) (KEY_OFF + 4u * (unsigned)(n))        // u16[n]
#define WS_NEED(n) ((size_t)SEG_OFF(n) + 2ull * (size_t)(n) + 256ull)

// Persistent device globals.
__device__ unsigned g_minkey;
__device__ unsigned g_maxkey;
// old-path tree (R8, proven)
__device__ unsigned long long g_grp[T_TOTAL][16][16];
__device__ unsigned long long g_top[T_TOTAL][16];
__device__ unsigned g_rel[T_TOTAL][32];
// new-path tree: 1024 -> 64 -> 4 -> 1, fan-out to 64 group-release words
__device__ unsigned long long g_n1[T_TOTAL][64][16];
__device__ unsigned long long g_n2[T_TOTAL][4][16];
__device__ unsigned long long g_n3[T_TOTAL][16];
__device__ unsigned g_relg[T_TOTAL][64][32];   // [s][group][0]: total+1

__device__ __forceinline__ unsigned f2key(float f) {
    unsigned b = __float_as_uint(f);
    return b ^ ((unsigned)(((int)b) >> 31) | 0x80000000u);
}
__device__ __forceinline__ float key2f(unsigned k) {
    unsigned b = (k & 0x80000000u) ? (k ^ 0x80000000u) : ~k;
    return __uint_as_float(b);
}

// Exact reference bin: ((t-tmin)/(tmax-tmin))*(10-1e-6), trunc, clip.
__device__ __forceinline__ int event_bin_t(float tv, float tmin, float tmax) {
#pragma clang fp contract(off)
    float tn;
    if (tmax > tmin) tn = (tv - tmin) / (tmax - tmin) * (float)(10.0 - 1e-6);
    else tn = 0.0f;
    int ti = (int)tn;
    return ti < 0 ? 0 : (ti > T_EVT - 1 ? T_EVT - 1 : ti);
}
__device__ __forceinline__ int event_pixel(int xi, int yi, int ci) {
    xi = xi < 0 ? 0 : (xi > WW - 1 ? WW - 1 : xi);
    yi = yi < 0 ? 0 : (yi > HH - 1 ? HH - 1 : yi);
    return ci * (HH * WW) + yi * WW + xi;
}

__global__ void init_kernel() {
    const int gtid = blockIdx.x * blockDim.x + threadIdx.x;
    const int gs = gridDim.x * blockDim.x;
    if (gtid == 0) { g_minkey = 0xFFFFFFFFu; g_maxkey = 0u; }
    unsigned long long* a = &g_grp[0][0][0];
    for (int i = gtid; i < T_TOTAL * 16 * 16; i += gs) a[i] = 0ull;
    unsigned long long* b = &g_top[0][0];
    for (int i = gtid; i < T_TOTAL * 16; i += gs) b[i] = 0ull;
    unsigned* c = &g_rel[0][0];
    for (int i = gtid; i < T_TOTAL * 32; i += gs) c[i] = 0u;
    unsigned long long* d = &g_n1[0][0][0];
    for (int i = gtid; i < T_TOTAL * 64 * 16; i += gs) d[i] = 0ull;
    unsigned long long* e = &g_n2[0][0][0];
    for (int i = gtid; i < T_TOTAL * 4 * 16; i += gs) e[i] = 0ull;
    unsigned long long* f = &g_n3[0][0];
    for (int i = gtid; i < T_TOTAL * 16; i += gs) f[i] = 0ull;
    unsigned* g = &g_relg[0][0][0];
    for (int i = gtid; i < T_TOTAL * 64 * 32; i += gs) g[i] = 0u;
}

// ======================= shared: t min/max =======================
__device__ __forceinline__ void minmax_body(const float* __restrict__ t, int n,
                                            int gtid, int gstride) {
    unsigned mn = 0xFFFFFFFFu, mx = 0u;
    const int n4 = n >> 2;
    const float4* t4 = (const float4*)t;
    for (int i = gtid; i < n4; i += gstride) {
        float4 tv = t4[i];
        unsigned k0 = f2key(tv.x), k1 = f2key(tv.y);
        unsigned k2 = f2key(tv.z), k3 = f2key(tv.w);
        unsigned a = k0 < k1 ? k0 : k1, b = k2 < k3 ? k2 : k3;
        unsigned c = a < b ? a : b;
        mn = mn < c ? mn : c;
        a = k0 > k1 ? k0 : k1; b = k2 > k3 ? k2 : k3;
        c = a > b ? a : b;
        mx = mx > c ? mx : c;
    }
    for (int i = (n4 << 2) + gtid; i < n; i += gstride) {
        unsigned k = f2key(t[i]);
        mn = mn < k ? mn : k;
        mx = mx > k ? mx : k;
    }
    for (int off = 32; off > 0; off >>= 1) {
        unsigned omn = (unsigned)__shfl_down((int)mn, off, 64);
        unsigned omx = (unsigned)__shfl_down((int)mx, off, 64);
        mn = mn < omn ? mn : omn;
        mx = mx > omx ? mx : omx;
    }
    __shared__ unsigned smn[16], smx[16];
    int lane = threadIdx.x & 63, wv = threadIdx.x >> 6;
    if (lane == 0) { smn[wv] = mn; smx[wv] = mx; }
    __syncthreads();
    if (threadIdx.x == 0) {
        int nw = blockDim.x >> 6;
        for (int i = 1; i < nw; ++i) {
            mn = mn < smn[i] ? mn : smn[i];
            mx = mx > smx[i] ? mx : smx[i];
        }
        atomicMin(&g_minkey, mn);
        atomicMax(&g_maxkey, mx);
    }
}

__global__ void minmax_kernel(const float* __restrict__ t, int n) {
    minmax_body(t, n, blockIdx.x * blockDim.x + threadIdx.x,
                gridDim.x * blockDim.x);
}

__global__ void minmax_zero_kernel(const float* __restrict__ t, int n,
                                   uint4* __restrict__ hist16v) {
    const int gtid = blockIdx.x * blockDim.x + threadIdx.x;
    const int gstride = gridDim.x * blockDim.x;
    const uint4 z = make_uint4(0u, 0u, 0u, 0u);
    const int nz = T_EVT * FRAME / 8;
    for (int i = gtid; i < nz; i += gstride) hist16v[i] = z;
    minmax_body(t, n, gtid, gstride);
}

// ======================= new path: counting sort =======================
// passA: decode events ONCE -> packed key (ti<<21 | pix) + LDS bucket counts.
// 512 blocks x 1024 thr = 32 waves/CU (was 1 wave/SIMD: latency-bound, R10).
__global__ __launch_bounds__(RTHR) void passA_kernel(
        const int* __restrict__ x, const int* __restrict__ y,
        const int* __restrict__ p, const float* __restrict__ t,
        unsigned* __restrict__ mat, unsigned* __restrict__ keys, int n) {
    __shared__ unsigned cnt[NBUCKET];
    for (int i = threadIdx.x; i < NBUCKET; i += blockDim.x) cnt[i] = 0u;
    __syncthreads();
    const float tmin = key2f(g_minkey);
    const float tmax = key2f(g_maxkey);
    const int chunk = (n + (int)gridDim.x - 1) / (int)gridDim.x;
    const int s0 = blockIdx.x * chunk;
    const int s1 = min(n, s0 + chunk);
    for (int i = s0 + threadIdx.x; i < s1; i += blockDim.x) {
        int pix = event_pixel(x[i], y[i], p[i]);
        int ti = event_bin_t(t[i], tmin, tmax);
        keys[i] = ((unsigned)ti << 21) | (unsigned)pix;   // pix < 2^21
        atomicAdd(&cnt[pix / PIXB], 1u);
    }
    __syncthreads();
    for (int i = threadIdx.x; i < NBUCKET; i += blockDim.x)
        mat[blockIdx.x * NBUCKET + i] = cnt[i];
}

// one block PER BUCKET COLUMN: exclusive scan of the 512 row counts.
__global__ void offsets_col_kernel(unsigned* __restrict__ mat,
                                   unsigned* __restrict__ colsum) {
    const int j = blockIdx.x;        // bucket
    const int r = threadIdx.x;       // row (passA block), 0..511
    const int lane = r & 63, wv = r >> 6;
    unsigned v = mat[r * NBUCKET + j];
    unsigned incl = v;
    for (int off = 1; off < 64; off <<= 1) {
        unsigned o = (unsigned)__shfl_up((int)incl, off, 64);
        if (lane >= off) incl += o;
    }
    __shared__ unsigned wtot[RBLK / 64];
    if (lane == 63) wtot[wv] = incl;
    __syncthreads();
    if (r == 0) {
        unsigned run = 0;
#pragma unroll
        for (int k = 0; k < RBLK / 64; ++k) { unsigned tmp = wtot[k]; wtot[k] = run; run += tmp; }
    }
    __syncthreads();
    unsigned ex = incl - v + wtot[wv];
    mat[r * NBUCKET + j] = ex;
    if (r == RBLK - 1) colsum[j] = ex + v;
}

// one block, 1024 threads: exclusive scan of bucket totals -> seg bases.
__global__ void offsets_top_kernel(const unsigned* __restrict__ colsum,
                                   unsigned* __restrict__ seg_base) {
    const int j = threadIdx.x;
    const int lane = j & 63, wv = j >> 6;
    unsigned v = colsum[j];
    unsigned incl = v;
    for (int off = 1; off < 64; off <<= 1) {
        unsigned o = (unsigned)__shfl_up((int)incl, off, 64);
        if (lane >= off) incl += o;
    }
    __shared__ unsigned wtot[16];
    if (lane == 63) wtot[wv] = incl;
    __syncthreads();
    if (j == 0) {
        unsigned run = 0;
#pragma unroll
        for (int k = 0; k < 16; ++k) { unsigned tmp = wtot[k]; wtot[k] = run; run += tmp; }
    }
    __syncthreads();
    unsigned ex = incl - v + wtot[wv];
    seg_base[j] = ex;
    if (j == NBUCKET - 1) seg_base[NBUCKET] = ex + v;
}

// passB: read packed keys only; LDS-rank; scatter u16 local bin.
__global__ __launch_bounds__(RTHR) void passB_kernel(
        const unsigned* __restrict__ keys, const unsigned* __restrict__ mat,
        const unsigned* __restrict__ seg_base,
        unsigned short* __restrict__ seg, int n) {
    __shared__ unsigned base[NBUCKET];
    for (int i = threadIdx.x; i < NBUCKET; i += blockDim.x)
        base[i] = mat[blockIdx.x * NBUCKET + i] + seg_base[i];
    __syncthreads();
    const int chunk = (n + (int)gridDim.x - 1) / (int)gridDim.x;
    const int s0 = blockIdx.x * chunk;
    const int s1 = min(n, s0 + chunk);
    for (int i = s0 + threadIdx.x; i < s1; i += blockDim.x) {
        unsigned k = keys[i];
        int pix = (int)(k & 0x1FFFFFu);
        int ti = (int)(k >> 21);
        int bkt = pix / PIXB;
        int lb = ti * PIXB + (pix - bkt * PIXB);   // < 18000
        unsigned idx = atomicAdd(&base[bkt], 1u);
        seg[idx] = (unsigned short)lb;
    }
}

// Cooperative scan, 1024 blocks x 256 thr, 36 KB LDS hist (R9, proven).
__global__ __launch_bounds__(STHR, 4) void scan_new(float* __restrict__ out,
                                                    const unsigned short* __restrict__ seg,
                                                    const unsigned* __restrict__ seg_base) {
#pragma clang fp contract(off)
    const float decay = (float)0.9048374180359595;  // float32(exp(-1/10))
    const int tid = threadIdx.x;
    const int lane = tid & 63;
    const int b = blockIdx.x;
    const int pix0 = b * PIXB;

    __shared__ unsigned lds_hist[HIST_W];
    __shared__ unsigned lds_arr[T_TOTAL];
    __shared__ unsigned lds_tot[T_TOTAL];

    for (int i = tid; i < HIST_W; i += STHR) lds_hist[i] = 0u;
    if (tid < T_TOTAL) { lds_arr[tid] = 0u; lds_tot[tid] = 0u; }
    __syncthreads();

    {
        const int e0 = (int)seg_base[b];
        const int e1 = (int)seg_base[b + 1];
        for (int i = e0 + tid; i < e1; i += STHR) {
            unsigned lb = seg[i];
            atomicAdd(&lds_hist[lb >> 1], 1u << ((lb & 1u) << 4));
        }
    }
    __syncthreads();

    const bool has1 = tid < (NGROUP4 - STHR);
    float4 mem0 = make_float4(0.f, 0.f, 0.f, 0.f);
    float4 mem1 = make_float4(0.f, 0.f, 0.f, 0.f);
    float thr = 1.0f;

    for (int s = 0; s < T_TOTAL; ++s) {
        float* ob = out + (size_t)s * FRAME + pix0;
        int cnt = 0;

        {
            float4 f;
            if (s < T_EVT) {
                int w = s * 900 + (tid << 1);
                unsigned w0 = lds_hist[w], w1 = lds_hist[w + 1];
                f = make_float4((float)(w0 & 0xFFFFu), (float)(w0 >> 16),
                                (float)(w1 & 0xFFFFu), (float)(w1 >> 16));
            } else f = make_float4(0.f, 0.f, 0.f, 0.f);
            float4 m, spk;
            m.x = mem0.x * decay; m.x = m.x + f.x;
            m.y = mem0.y * decay; m.y = m.y + f.y;
            m.z = mem0.z * decay; m.z = m.z + f.z;
            m.w = mem0.w * decay; m.w = m.w + f.w;
            spk.x = (m.x >= thr) ? 1.0f : 0.0f;
            spk.y = (m.y >= thr) ? 1.0f : 0.0f;
            spk.z = (m.z >= thr) ? 1.0f : 0.0f;
            spk.w = (m.w >= thr) ? 1.0f : 0.0f;
            ((float4*)ob)[tid] = spk;
            mem0.x = m.x - spk.x * thr;
            mem0.y = m.y - spk.y * thr;
            mem0.z = m.z - spk.z * thr;
            mem0.w = m.w - spk.w * thr;
            cnt += (int)spk.x + (int)spk.y + (int)spk.z + (int)spk.w;
        }
        if (has1) {
            int g = tid + STHR;
            float4 f;
            if (s < T_EVT) {
                int w = s * 900 + (g << 1);
                unsigned w0 = lds_hist[w], w1 = lds_hist[w + 1];
                f = make_float4((float)(w0 & 0xFFFFu), (float)(w0 >> 16),
                                (float)(w1 & 0xFFFFu), (float)(w1 >> 16));
            } else f = make_float4(0.f, 0.f, 0.f, 0.f);
            float4 m, spk;
            m.x = mem1.x * decay; m.x = m.x + f.x;
            m.y = mem1.y * decay; m.y = m.y + f.y;
            m.z = mem1.z * decay; m.z = m.z + f.z;
            m.w = mem1.w * decay; m.w = m.w + f.w;
            spk.x = (m.x >= thr) ? 1.0f : 0.0f;
            spk.y = (m.y >= thr) ? 1.0f : 0.0f;
            spk.z = (m.z >= thr) ? 1.0f : 0.0f;
            spk.w = (m.w >= thr) ? 1.0f : 0.0f;
            ((float4*)ob)[g] = spk;
            mem1.x = m.x - spk.x * thr;
            mem1.y = m.y - spk.y * thr;
            mem1.z = m.z - spk.z * thr;
            mem1.w = m.w - spk.w * thr;
            cnt += (int)spk.x + (int)spk.y + (int)spk.z + (int)spk.w;
        }

        if (s == T_TOTAL - 1) break;

        for (int off = 32; off > 0; off >>= 1) cnt += __shfl_down(cnt, off, 64);
        unsigned total;
        if (lane == 0) {
            unsigned old = __hip_atomic_fetch_add(&lds_arr[s],
                               (unsigned)cnt + (1u << 16),
                               __ATOMIC_RELAXED, __HIP_MEMORY_SCOPE_WORKGROUP);
            if ((old >> 16) == SWPB - 1) {
                unsigned bc = (old + (unsigned)cnt) & 0xFFFFu;
                const int g1 = b >> 4;
                unsigned long long a1 = __hip_atomic_fetch_add(
                    &g_n1[s][g1][0], (unsigned long long)bc + ARRIVE64,
                    __ATOMIC_RELAXED, __HIP_MEMORY_SCOPE_AGENT);
                if ((unsigned)(a1 >> 32) == 15u) {
                    unsigned c1 = (unsigned)a1 + bc;
                    const int g2 = g1 >> 4;
                    unsigned long long a2 = __hip_atomic_fetch_add(
                        &g_n2[s][g2][0], (unsigned long long)c1 + ARRIVE64,
                        __ATOMIC_RELAXED, __HIP_MEMORY_SCOPE_AGENT);
                    if ((unsigned)(a2 >> 32) == 15u) {
                        unsigned c2 = (unsigned)a2 + c1;
                        unsigned long long a3 = __hip_atomic_fetch_add(
                            &g_n3[s][0], (unsigned long long)c2 + ARRIVE64,
                            __ATOMIC_RELAXED, __HIP_MEMORY_SCOPE_AGENT);
                        if ((unsigned)(a3 >> 32) == 3u) {
                            unsigned tot = (unsigned)a3 + c2;
                            for (int g = 0; g < 64; ++g)
                                __hip_atomic_store(&g_relg[s][g][0], tot + 1u,
                                    __ATOMIC_RELAXED, __HIP_MEMORY_SCOPE_AGENT);
                        }
                    }
                }
                unsigned f;
                do {
                    __builtin_amdgcn_s_sleep(1);
                    f = __hip_atomic_load(&g_relg[s][g1][0], __ATOMIC_RELAXED,
                                          __HIP_MEMORY_SCOPE_AGENT);
                } while (f == 0u);
                total = f - 1u;
                __hip_atomic_store(&lds_tot[s], f,
                                   __ATOMIC_RELAXED, __HIP_MEMORY_SCOPE_WORKGROUP);
            } else {
                unsigned f;
                do {
                    __builtin_amdgcn_s_sleep(1);
                    f = __hip_atomic_load(&lds_tot[s], __ATOMIC_RELAXED,
                                          __HIP_MEMORY_SCOPE_WORKGROUP);
                } while (f == 0u);
                total = f - 1u;
            }
        }
        total = (unsigned)__shfl((int)total, 0, 64);
        float rate = (float)total / 1843200.0f;
        thr = thr + 0.1f * (rate - 0.1f);
        thr = fminf(fmaxf(thr, 0.1f), 10.0f);
    }
}

// ======================= old (fallback) path =======================
__global__ void scatter_kernel(const int* __restrict__ x, const int* __restrict__ y,
                               const int* __restrict__ p, const float* __restrict__ t,
                               unsigned* __restrict__ hist32, int n) {
    int i = blockIdx.x * blockDim.x + threadIdx.x;
    if (i >= n) return;
    float tmin = key2f(g_minkey);
    float tmax = key2f(g_maxkey);
    int ti = event_bin_t(t[i], tmin, tmax);
    int pix = event_pixel(x[i], y[i], p[i]);
    size_t bidx = (size_t)ti * FRAME + pix;
    atomicAdd(hist32 + (bidx >> 1), 1u << ((bidx & 1) << 4));
}

__global__ __launch_bounds__(ONTHR) void scan_old(float* __restrict__ out) {
#pragma clang fp contract(off)
    const float decay = (float)0.9048374180359595;
    const int gtid = blockIdx.x * ONTHR + threadIdx.x;
    const int lane = threadIdx.x & 63;
    const uint2 uz2 = make_uint2(0u, 0u);
    float4 mem0 = make_float4(0.f, 0.f, 0.f, 0.f);
    float4 mem1 = make_float4(0.f, 0.f, 0.f, 0.f);
    const bool has1 = (gtid + ONT) < FRAME4;
    float thr = 1.0f;
    const uint2* hist2 = (const uint2*)(out + (size_t)T_EVT * FRAME);
    __shared__ unsigned lds_arr[T_TOTAL];
    __shared__ unsigned lds_tot[T_TOTAL];
    if (threadIdx.x < T_TOTAL) { lds_arr[threadIdx.x] = 0u; lds_tot[threadIdx.x] = 0u; }
    __syncthreads();
    uint2 u0 = hist2[gtid];
    uint2 u1 = has1 ? hist2[gtid + ONT] : uz2;
    for (int s = 0; s < T_TOTAL; ++s) {
        float4* o4 = (float4*)(out + (size_t)s * FRAME);
        int cnt = 0;
        {
            float4 m, spk;
            m.x = mem0.x * decay; m.x = m.x + (float)(u0.x & 0xFFFFu);
            m.y = mem0.y * decay; m.y = m.y + (float)(u0.x >> 16);
            m.z = mem0.z * decay; m.z = m.z + (float)(u0.y & 0xFFFFu);
            m.w = mem0.w * decay; m.w = m.w + (float)(u0.y >> 16);
            spk.x = (m.x >= thr) ? 1.0f : 0.0f;
            spk.y = (m.y >= thr) ? 1.0f : 0.0f;
            spk.z = (m.z >= thr) ? 1.0f : 0.0f;
            spk.w = (m.w >= thr) ? 1.0f : 0.0f;
            o4[gtid] = spk;
            mem0.x = m.x - spk.x * thr; mem0.y = m.y - spk.y * thr;
            mem0.z = m.z - spk.z * thr; mem0.w = m.w - spk.w * thr;
            cnt += (int)spk.x + (int)spk.y + (int)spk.z + (int)spk.w;
        }
        if (has1) {
            float4 m, spk;
            m.x = mem1.x * decay; m.x = m.x + (float)(u1.x & 0xFFFFu);
            m.y = mem1.y * decay; m.y = m.y + (float)(u1.x >> 16);
            m.z = mem1.z * decay; m.z = m.z + (float)(u1.y & 0xFFFFu);
            m.w = mem1.w * decay; m.w = m.w + (float)(u1.y >> 16);
            spk.x = (m.x >= thr) ? 1.0f : 0.0f;
            spk.y = (m.y >= thr) ? 1.0f : 0.0f;
            spk.z = (m.z >= thr) ? 1.0f : 0.0f;
            spk.w = (m.w >= thr) ? 1.0f : 0.0f;
            o4[gtid + ONT] = spk;
            mem1.x = m.x - spk.x * thr; mem1.y = m.y - spk.y * thr;
            mem1.z = m.z - spk.z * thr; mem1.w = m.w - spk.w * thr;
            cnt += (int)spk.x + (int)spk.y + (int)spk.z + (int)spk.w;
        }
        if (s + 1 < T_EVT) {
            const uint2* hn = hist2 + (size_t)(s + 1) * FRAME4;
            u0 = hn[gtid];
            u1 = has1 ? hn[gtid + ONT] : uz2;
        } else { u0 = uz2; u1 = uz2; }
        if (s == T_TOTAL - 1) break;
        for (int off = 32; off > 0; off >>= 1) cnt += __shfl_down(cnt, off, 64);
        unsigned total;
        if (lane == 0) {
            unsigned old = __hip_atomic_fetch_add(&lds_arr[s],
                               (unsigned)cnt + (1u << 16),
                               __ATOMIC_RELAXED, __HIP_MEMORY_SCOPE_WORKGROUP);
            if ((old >> 16) == ONWPB - 1) {
                unsigned bc = (old + (unsigned)cnt) & 0xFFFFu;
                const int gid = blockIdx.x >> 4;
                unsigned long long gold = __hip_atomic_fetch_add(
                    &g_grp[s][gid][0], (unsigned long long)bc + ARRIVE64,
                    __ATOMIC_RELAXED, __HIP_MEMORY_SCOPE_AGENT);
                if ((unsigned)(gold >> 32) == 15u) {
                    unsigned gc = (unsigned)gold + bc;
                    unsigned long long told = __hip_atomic_fetch_add(
                        &g_top[s][0], (unsigned long long)gc + ARRIVE64,
                        __ATOMIC_RELAXED, __HIP_MEMORY_SCOPE_AGENT);
                    if ((unsigned)(told >> 32) == 15u) {
                        unsigned tot = (unsigned)told + gc;
                        __hip_atomic_store(&g_rel[s][0], tot + 1u,
                                           __ATOMIC_RELAXED, __HIP_MEMORY_SCOPE_AGENT);
                    }
                }
                unsigned f;
                do {
                    __builtin_amdgcn_s_sleep(1);
                    f = __hip_atomic_load(&g_rel[s][0], __ATOMIC_RELAXED,
                                          __HIP_MEMORY_SCOPE_AGENT);
                } while (f == 0u);
                total = f - 1u;
                __hip_atomic_store(&lds_tot[s], f,
                                   __ATOMIC_RELAXED, __HIP_MEMORY_SCOPE_WORKGROUP);
            } else {
                unsigned f;
                do {
                    __builtin_amdgcn_s_sleep(1);
                    f = __hip_atomic_load(&lds_tot[s], __ATOMIC_RELAXED,
                                          __HIP_MEMORY_SCOPE_WORKGROUP);
                } while (f == 0u);
                total = f - 1u;
            }
        }
        total = (unsigned)__shfl((int)total, 0, 64);
        float rate = (float)total / 1843200.0f;
        thr = thr + 0.1f * (rate - 0.1f);
        thr = fminf(fmaxf(thr, 0.1f), 10.0f);
    }
}

extern "C" void kernel_launch(void* const* d_in, const int* in_sizes, int n_in,
                              void* d_out, int out_size, void* d_ws, size_t ws_size,
                              hipStream_t stream) {
    const int*   x = (const int*)d_in[0];
    const int*   y = (const int*)d_in[1];
    const int*   p = (const int*)d_in[2];
    const float* t = (const float*)d_in[3];
    float* out = (float*)d_out;
    const int n = in_sizes[0];

    init_kernel<<<64, 256, 0, stream>>>();

    if (d_ws != nullptr && ws_size >= WS_NEED(n)) {
        unsigned* mat = (unsigned*)((char*)d_ws + MAT_OFF);
        unsigned* colsum = (unsigned*)((char*)d_ws + CS_OFF);
        unsigned* seg_base = (unsigned*)((char*)d_ws + SB_OFF);
        unsigned* keys = (unsigned*)((char*)d_ws + KEY_OFF);
        unsigned short* seg = (unsigned short*)((char*)d_ws + SEG_OFF(n));

        minmax_kernel<<<1024, 256, 0, stream>>>(t, n);
        passA_kernel<<<RBLK, RTHR, 0, stream>>>(x, y, p, t, mat, keys, n);
        offsets_col_kernel<<<NBUCKET, RBLK, 0, stream>>>(mat, colsum);
        offsets_top_kernel<<<1, NBUCKET, 0, stream>>>(colsum, seg_base);
        passB_kernel<<<RBLK, RTHR, 0, stream>>>(keys, mat, seg_base, seg, n);

        dim3 g(SBLK), b(STHR);
        void* args[] = { (void*)&out, (void*)&seg, (void*)&seg_base };
        hipLaunchCooperativeKernel((void*)scan_new, g, b, args, 0, stream);
    } else {
        unsigned* hist32 = (unsigned*)(out + (size_t)T_EVT * FRAME);
        minmax_zero_kernel<<<1024, 256, 0, stream>>>(t, n, (uint4*)hist32);
        scatter_kernel<<<(n + 255) / 256, 256, 0, stream>>>(x, y, p, t, hist32, n);
        dim3 g(ONBLK), b(ONTHR);
        void* args[] = { (void*)&out };
        hipLaunchCooperativeKernel((void*)scan_old, g, b, args, 0, stream);
    }
}